// Round 3
// baseline (6799.546 us; speedup 1.0000x reference)
//
#include <hip/hip_runtime.h>

#define SLEN 400
#define BATCH 32
#define TLEN 16
#define NDEC 15
#define EDIM 128
#define HDIM 256
#define H3 768
#define VVOC 50000
#define VEXT 50020

// ---------- fast math helpers ----------
__device__ __forceinline__ float frcp(float x){ return __builtin_amdgcn_rcpf(x); }
__device__ __forceinline__ float fsig(float x){ return frcp(1.f + __expf(-x)); }
__device__ __forceinline__ float ftanh(float x){
  float e = __expf(2.f*x);
  return 1.f - 2.f*frcp(e + 1.f);
}

__device__ __forceinline__ float wred_max(float v){
  #pragma unroll
  for (int o=32;o>0;o>>=1) v = fmaxf(v, __shfl_down(v,o,64));
  return v;
}
__device__ __forceinline__ float wred_sum(float v){
  #pragma unroll
  for (int o=32;o>0;o>>=1) v += __shfl_down(v,o,64);
  return v;
}
__device__ __forceinline__ float block_max(float v, float* red){
  v = wred_max(v);
  int lane = threadIdx.x & 63, wid = threadIdx.x >> 6;
  if (!lane) red[wid] = v;
  __syncthreads();
  if (threadIdx.x == 0){
    float m = red[0];
    int nw = blockDim.x >> 6;
    for (int w=1;w<nw;++w) m = fmaxf(m, red[w]);
    red[0] = m;
  }
  __syncthreads();
  v = red[0];
  __syncthreads();
  return v;
}
__device__ __forceinline__ float block_sum(float v, float* red){
  v = wred_sum(v);
  int lane = threadIdx.x & 63, wid = threadIdx.x >> 6;
  if (!lane) red[wid] = v;
  __syncthreads();
  if (threadIdx.x == 0){
    float m = red[0];
    int nw = blockDim.x >> 6;
    for (int w=1;w<nw;++w) m += red[w];
    red[0] = m;
  }
  __syncthreads();
  v = red[0];
  __syncthreads();
  return v;
}

// ---------- embedding gather: src sequence (S,B,E) + decoder tokens into cat_all[:,0:128] ----------
__global__ __launch_bounds__(64) void k_embed(
    const int* __restrict__ input_seq, const int* __restrict__ target_seq,
    const float* __restrict__ embedding,
    float* __restrict__ emb_src, float* __restrict__ cat_all)
{
  int row = blockIdx.x;
  int tok; float* dst;
  if (row < SLEN*BATCH) {
    int s = row >> 5, b = row & 31;
    tok = input_seq[b*SLEN + s];
    dst = emb_src + (size_t)row*EDIM;
  } else {
    int rr = row - SLEN*BATCH;
    int t = rr >> 5, b = rr & 31;
    tok = target_seq[b*TLEN + t];       // toks = target_seq[:, :T-1].T
    dst = cat_all + (size_t)rr*896;     // cat cols [0:128) = e
  }
  const float2* src = (const float2*)(embedding + (size_t)tok*EDIM);
  ((float2*)dst)[threadIdx.x] = src[threadIdx.x];
}

// ---------- generic tiled GEMM: C[m,n] = sum_k A[am,k]*W[n,k] + bias[n] ----------
// rev=1 remaps A row m=(s*32+b) -> ((S-1-s)*32+b)   (for backward-direction gi)
#define GBM 128
#define GBN 128
#define GBK 32
__global__ __launch_bounds__(256) void k_gemm(
    const float* __restrict__ A, int lda,
    const float* __restrict__ W, int ldw,
    const float* __restrict__ bias,
    float* __restrict__ C, int ldc,
    int M, int N, int K, int rev)
{
  __shared__ float As[GBK][GBM+4];
  __shared__ float Ws[GBK][GBN+4];
  int tid = threadIdx.x;
  int ty = tid >> 4, tx = tid & 15;
  int m0 = blockIdx.y*GBM, n0 = blockIdx.x*GBN;
  float acc[8][8];
  #pragma unroll
  for (int i=0;i<8;++i)
    #pragma unroll
    for (int jj=0;jj<8;++jj) acc[i][jj] = 0.f;

  for (int k0=0;k0<K;k0+=GBK){
    #pragma unroll
    for (int i=0;i<4;++i){
      int idx = tid + i*256;
      int row = idx >> 3, c4 = idx & 7;
      int m = m0 + row, k = k0 + c4*4;
      float4 v = {0.f,0.f,0.f,0.f};
      if (m < M){
        int am = m;
        if (rev){ int s = m >> 5; am = ((SLEN-1-s)<<5) | (m&31); }
        v = *(const float4*)&A[(size_t)am*lda + k];
      }
      As[c4*4+0][row]=v.x; As[c4*4+1][row]=v.y; As[c4*4+2][row]=v.z; As[c4*4+3][row]=v.w;
    }
    #pragma unroll
    for (int i=0;i<4;++i){
      int idx = tid + i*256;
      int row = idx >> 3, c4 = idx & 7;
      int n = n0 + row, k = k0 + c4*4;
      float4 v = {0.f,0.f,0.f,0.f};
      if (n < N) v = *(const float4*)&W[(size_t)n*ldw + k];
      Ws[c4*4+0][row]=v.x; Ws[c4*4+1][row]=v.y; Ws[c4*4+2][row]=v.z; Ws[c4*4+3][row]=v.w;
    }
    __syncthreads();
    #pragma unroll 4
    for (int kk=0;kk<GBK;++kk){
      float4 a0 = *(const float4*)&As[kk][ty*8];
      float4 a1 = *(const float4*)&As[kk][ty*8+4];
      float4 b0 = *(const float4*)&Ws[kk][tx*8];
      float4 b1 = *(const float4*)&Ws[kk][tx*8+4];
      float av[8]={a0.x,a0.y,a0.z,a0.w,a1.x,a1.y,a1.z,a1.w};
      float bv[8]={b0.x,b0.y,b0.z,b0.w,b1.x,b1.y,b1.z,b1.w};
      #pragma unroll
      for (int i=0;i<8;++i)
        #pragma unroll
        for (int jj=0;jj<8;++jj) acc[i][jj]=fmaf(av[i],bv[jj],acc[i][jj]);
    }
    __syncthreads();
  }
  #pragma unroll
  for (int i=0;i<8;++i){
    int m = m0 + ty*8 + i;
    if (m < M){
      #pragma unroll
      for (int jj=0;jj<8;++jj){
        int n = n0 + tx*8 + jj;
        if (n < N) C[(size_t)m*ldc + n] = acc[i][jj] + bias[n];
      }
    }
  }
}

// ---------- encoder GRU recurrence, persistent weights in NAMED registers ----------
// block = (dir, b), 1024 threads = 16 waves. j = tid&255 owns output element j of
// each gate; slice = tid>>8 owns k-columns [slice*64, slice*64+64). The 192 weight
// floats are 48 NAMED float4 values (macro-expanded) so SROA cannot demote them to
// scratch (round-2 failure: float w[3][64] alloca -> 240 MB spill traffic, VGPR=64).
#define R16(M) M(0) M(1) M(2) M(3) M(4) M(5) M(6) M(7) M(8) M(9) M(10) M(11) M(12) M(13) M(14) M(15)

__global__ __launch_bounds__(1024, 4) void k_enc(
    const float* __restrict__ gi_f, const float* __restrict__ gi_b,
    const float* __restrict__ Whh_f, const float* __restrict__ bhh_f,
    const float* __restrict__ Whh_b, const float* __restrict__ bhh_b,
    float* __restrict__ enc_states)
{
  int dir = blockIdx.x >> 5, b = blockIdx.x & 31;
  int tid = threadIdx.x;
  int j = tid & 255;
  int slice = tid >> 8;          // wave-uniform
  int k0 = slice * 64;
  const float* gi  = dir ? gi_b  : gi_f;
  const float* Whh = dir ? Whh_b : Whh_f;
  const float* bhh = dir ? bhh_b : bhh_f;

  __shared__ float h_s[HDIM];
  __shared__ float pr[3][4][HDIM];     // k-slice partials (12 KB)

  // persistent weights -> 48 named float4 registers
#define DW(i) float4 wa##i, wb##i, wc##i;
  R16(DW)
#undef DW
  {
    const float4* s0 = (const float4*)(Whh + (size_t)(0*HDIM + j)*HDIM + k0);
    const float4* s1 = (const float4*)(Whh + (size_t)(1*HDIM + j)*HDIM + k0);
    const float4* s2 = (const float4*)(Whh + (size_t)(2*HDIM + j)*HDIM + k0);
#define LW(i) wa##i = s0[i]; wb##i = s1[i]; wc##i = s2[i];
    R16(LW)
#undef LW
  }
  float bh0 = bhh[j], bh1 = bhh[HDIM+j], bh2 = bhh[2*HDIM+j];
  if (tid < HDIM) h_s[tid] = 0.f;
  float* dst = enc_states + (size_t)b*2*HDIM + dir*HDIM + j;
  __syncthreads();

  for (int s=0;s<SLEN;++s){
    // prefetch this step's input gates (only slice-0 waves need them);
    // loads issue here, waitcnt lands after the FMA phase -> latency hidden
    float ir=0.f, iz=0.f, inn=0.f;
    if (slice == 0){
      const float* g = gi + ((size_t)s*BATCH + b)*H3;
      ir = g[j]; iz = g[HDIM+j]; inn = g[2*HDIM+j];
    }
    // partial dots: h broadcast-read from LDS (wave-uniform addr), weights in regs
    float a0=0.f, a1=0.f, a2=0.f;
    const float4* h4p = (const float4*)&h_s[k0];
#define FM(i) { float4 h4 = h4p[i]; \
    a0=fmaf(wa##i.x,h4.x,a0); a0=fmaf(wa##i.y,h4.y,a0); a0=fmaf(wa##i.z,h4.z,a0); a0=fmaf(wa##i.w,h4.w,a0); \
    a1=fmaf(wb##i.x,h4.x,a1); a1=fmaf(wb##i.y,h4.y,a1); a1=fmaf(wb##i.z,h4.z,a1); a1=fmaf(wb##i.w,h4.w,a1); \
    a2=fmaf(wc##i.x,h4.x,a2); a2=fmaf(wc##i.y,h4.y,a2); a2=fmaf(wc##i.z,h4.z,a2); a2=fmaf(wc##i.w,h4.w,a2); }
    R16(FM)
#undef FM
    pr[0][slice][j]=a0; pr[1][slice][j]=a1; pr[2][slice][j]=a2;
    __syncthreads();
    if (slice == 0){
      float hr = ((pr[0][0][j]+pr[0][1][j])+(pr[0][2][j]+pr[0][3][j]))+bh0;
      float hz = ((pr[1][0][j]+pr[1][1][j])+(pr[1][2][j]+pr[1][3][j]))+bh1;
      float hn = ((pr[2][0][j]+pr[2][1][j])+(pr[2][2][j]+pr[2][3][j]))+bh2;
      float rr = fsig(ir+hr), zz = fsig(iz+hz);
      float nn = ftanh(inn + rr*hn);
      float hp = h_s[j];
      float h2 = nn + zz*(hp-nn);       // (1-z)*n + z*h
      h_s[j] = h2;
      int srow = dir ? (SLEN-1-s) : s;
      dst[(size_t)srow*BATCH*2*HDIM] = h2;
    }
    __syncthreads();
  }
}

// ---------- bridge: h0 = tanh([hf,hb] @ bridge_W.T + b) ----------
__global__ __launch_bounds__(256) void k_bridge(
    const float* __restrict__ enc_states,
    const float* __restrict__ bridge_W, const float* __restrict__ bridge_b,
    float* __restrict__ h_dec)
{
  int b = blockIdx.x, j = threadIdx.x;
  __shared__ float hcat[2*HDIM];
  hcat[j]        = enc_states[((size_t)(SLEN-1)*BATCH + b)*2*HDIM + j];          // forward final
  hcat[HDIM + j] = enc_states[(size_t)b*2*HDIM + HDIM + j];                      // backward final (s=0 slot)
  __syncthreads();
  const float* w = bridge_W + (size_t)j*2*HDIM;
  float4 a = {0.f,0.f,0.f,0.f};
  #pragma unroll 4
  for (int k=0;k<2*HDIM;k+=4){
    float4 h4 = *(const float4*)&hcat[k];
    float4 w4 = *(const float4*)&w[k];
    a.x=fmaf(h4.x,w4.x,a.x); a.y=fmaf(h4.y,w4.y,a.y);
    a.z=fmaf(h4.z,w4.z,a.z); a.w=fmaf(h4.w,w4.w,a.w);
  }
  h_dec[b*HDIM+j] = ftanh((a.x+a.y)+(a.z+a.w) + bridge_b[j]);
}

// ---------- one decoder step: attention + context + GRU (block = batch row) ----------
__global__ __launch_bounds__(256) void k_dec_step(
    int t,
    const float* __restrict__ proj,
    const float* __restrict__ enc_states,
    const float* __restrict__ attn_Wq,
    const float* __restrict__ attn_We,
    const float* __restrict__ dec_Wih,
    const float* __restrict__ dec_Whh,
    const float* __restrict__ dec_bhh,
    const float* __restrict__ gie_all,
    float* __restrict__ h_dec,
    float* __restrict__ alphas_all,
    float* __restrict__ cat_all)
{
  int b = blockIdx.x, j = threadIdx.x;
  __shared__ float h_s[HDIM], q_s[HDIM], we_s[HDIM], ctx_s[2*HDIM], sc[SLEN];
  __shared__ float red[8];
  h_s[j] = h_dec[b*HDIM + j];
  we_s[j] = attn_We[j];
  __syncthreads();
  // q = h @ Wq.T
  {
    const float* wq = attn_Wq + (size_t)j*HDIM;
    float4 a = {0.f,0.f,0.f,0.f};
    #pragma unroll 8
    for (int k=0;k<HDIM;k+=4){
      float4 h4 = *(const float4*)&h_s[k];
      float4 w4 = *(const float4*)&wq[k];
      a.x=fmaf(h4.x,w4.x,a.x); a.y=fmaf(h4.y,w4.y,a.y);
      a.z=fmaf(h4.z,w4.z,a.z); a.w=fmaf(h4.w,w4.w,a.w);
    }
    q_s[j] = (a.x+a.y)+(a.z+a.w);
  }
  __syncthreads();
  // scores[s] = tanh(q + proj[s,b]) . We
  for (int s=j; s<SLEN; s+=256){
    const float* pr = proj + ((size_t)s*BATCH + b)*HDIM;
    float4 a = {0.f,0.f,0.f,0.f};
    #pragma unroll 4
    for (int k=0;k<HDIM;k+=4){
      float4 p4 = *(const float4*)&pr[k];
      float4 q4 = *(const float4*)&q_s[k];
      float4 w4 = *(const float4*)&we_s[k];
      a.x = fmaf(ftanh(q4.x+p4.x), w4.x, a.x);
      a.y = fmaf(ftanh(q4.y+p4.y), w4.y, a.y);
      a.z = fmaf(ftanh(q4.z+p4.z), w4.z, a.z);
      a.w = fmaf(ftanh(q4.w+p4.w), w4.w, a.w);
    }
    sc[s] = (a.x+a.y)+(a.z+a.w);
  }
  __syncthreads();
  // softmax over s
  float m = -1e30f;
  for (int s=j; s<SLEN; s+=256) m = fmaxf(m, sc[s]);
  m = block_max(m, red);
  float ssum = 0.f;
  for (int s=j; s<SLEN; s+=256){ float e = __expf(sc[s]-m); sc[s]=e; ssum+=e; }
  ssum = block_sum(ssum, red);
  float inv = 1.f/ssum;
  for (int s=j; s<SLEN; s+=256){
    float a = sc[s]*inv; sc[s]=a;
    alphas_all[((size_t)t*SLEN + s)*BATCH + b] = a;
  }
  __syncthreads();
  int r = t*BATCH + b;
  // context = sum_s alpha[s] * enc_states[s,b,:]
  for (int d=j; d<2*HDIM; d+=256){
    const float* e0 = enc_states + (size_t)b*2*HDIM + d;
    float a0=0.f,a1=0.f,a2=0.f,a3=0.f;
    #pragma unroll 4
    for (int s=0;s<SLEN;s+=4){
      a0 = fmaf(sc[s+0], e0[(size_t)(s+0)*BATCH*2*HDIM], a0);
      a1 = fmaf(sc[s+1], e0[(size_t)(s+1)*BATCH*2*HDIM], a1);
      a2 = fmaf(sc[s+2], e0[(size_t)(s+2)*BATCH*2*HDIM], a2);
      a3 = fmaf(sc[s+3], e0[(size_t)(s+3)*BATCH*2*HDIM], a3);
    }
    float c = (a0+a1)+(a2+a3);
    ctx_s[d] = c;
    cat_all[(size_t)r*896 + 384 + d] = c;   // cat cols [384:896) = context
  }
  __syncthreads();
  // GRU cell: x = [e, context]; e-part (incl. bih) precomputed in gie_all
  float g[3], hh[3];
  #pragma unroll
  for (int gg=0; gg<3; ++gg){
    int jj = gg*HDIM + j;
    const float* wi = dec_Wih + (size_t)jj*640 + 128;   // ctx columns
    float4 a = {0.f,0.f,0.f,0.f};
    #pragma unroll 4
    for (int k=0;k<2*HDIM;k+=4){
      float4 c4 = *(const float4*)&ctx_s[k];
      float4 w4 = *(const float4*)&wi[k];
      a.x=fmaf(c4.x,w4.x,a.x); a.y=fmaf(c4.y,w4.y,a.y);
      a.z=fmaf(c4.z,w4.z,a.z); a.w=fmaf(c4.w,w4.w,a.w);
    }
    g[gg] = gie_all[(size_t)r*H3 + jj] + (a.x+a.y)+(a.z+a.w);
    const float* wh = dec_Whh + (size_t)jj*HDIM;
    float4 h4a = {0.f,0.f,0.f,0.f};
    #pragma unroll 4
    for (int k=0;k<HDIM;k+=4){
      float4 h4 = *(const float4*)&h_s[k];
      float4 w4 = *(const float4*)&wh[k];
      h4a.x=fmaf(h4.x,w4.x,h4a.x); h4a.y=fmaf(h4.y,w4.y,h4a.y);
      h4a.z=fmaf(h4.z,w4.z,h4a.z); h4a.w=fmaf(h4.w,w4.w,h4a.w);
    }
    hh[gg] = dec_bhh[jj] + (h4a.x+h4a.y)+(h4a.z+h4a.w);
  }
  float rr = fsig(g[0]+hh[0]);
  float zz = fsig(g[1]+hh[1]);
  float nn = ftanh(g[2] + rr*hh[2]);
  float h2 = nn + zz*(h_s[j]-nn);
  h_dec[b*HDIM + j] = h2;
  cat_all[(size_t)r*896 + 128 + j] = h2;    // cat cols [128:384) = h2
}

// ---------- p_gen = sigmoid(cat . pgen_W + b) ----------
__global__ __launch_bounds__(64) void k_pgen(
    const float* __restrict__ cat_all,
    const float* __restrict__ pgen_W, const float* __restrict__ pgen_b,
    float* __restrict__ pgen_all)
{
  int r = blockIdx.x;
  const float* c = cat_all + (size_t)r*896;
  float acc = 0.f;
  for (int k=threadIdx.x; k<896; k+=64) acc = fmaf(c[k], pgen_W[k], acc);
  acc = wred_sum(acc);
  if (threadIdx.x==0) pgen_all[r] = fsig(acc + pgen_b[0]);
}

// ---------- per-row softmax stats over V ----------
__global__ __launch_bounds__(256) void k_rowred(
    const float* __restrict__ logits,
    float* __restrict__ row_max, float* __restrict__ row_sum)
{
  int r = blockIdx.x;
  const float4* row = (const float4*)(logits + (size_t)r*VVOC);
  __shared__ float red[8];
  float m = -1e30f;
  for (int v=threadIdx.x; v<VVOC/4; v+=256){
    float4 x = row[v];
    m = fmaxf(m, fmaxf(fmaxf(x.x,x.y), fmaxf(x.z,x.w)));
  }
  m = block_max(m, red);
  float s = 0.f;
  for (int v=threadIdx.x; v<VVOC/4; v+=256){
    float4 x = row[v];
    s += __expf(x.x-m) + __expf(x.y-m) + __expf(x.z-m) + __expf(x.w-m);
  }
  s = block_sum(s, red);
  if (threadIdx.x==0){ row_max[r]=m; row_sum[r]=1.f/s; }
}

// ---------- write ext (linear domain) for all (t,b,v); t=0 row = 0 ----------
__global__ __launch_bounds__(256) void k_final(
    const float* __restrict__ logits, const float* __restrict__ pgen_all,
    const float* __restrict__ row_max, const float* __restrict__ row_sum,
    float* __restrict__ out)
{
  int v = blockIdx.x*256 + threadIdx.x;
  if (v >= VEXT) return;
  int b = blockIdx.y, t = blockIdx.z;
  size_t o = ((size_t)t*BATCH + b)*VEXT + v;
  if (t == 0){ out[o] = 0.f; return; }
  int r = (t-1)*BATCH + b;
  float val = 1e-12f;
  if (v < VVOC)
    val += pgen_all[r] * row_sum[r] * __expf(logits[(size_t)r*VVOC + v] - row_max[r]);
  out[o] = val;
}

// ---------- scatter copy-distribution ----------
__global__ __launch_bounds__(512) void k_scatter(
    const int* __restrict__ input_seq_ext,
    const float* __restrict__ alphas, const float* __restrict__ pgen_all,
    float* __restrict__ out)
{
  int r = blockIdx.x;               // t*32+b
  int s = threadIdx.x;
  if (s >= SLEN) return;
  int t = r >> 5, b = r & 31;
  float w = (1.f - pgen_all[r]) * alphas[((size_t)t*SLEN + s)*BATCH + b];
  int idx = input_seq_ext[b*SLEN + s];
  atomicAdd(&out[((size_t)(t+1)*BATCH + b)*VEXT + idx], w);
}

// ---------- log transform rows t>=1 ----------
__global__ __launch_bounds__(256) void k_log(float* __restrict__ out)
{
  int v = blockIdx.x*256 + threadIdx.x;
  if (v >= VEXT) return;
  int b = blockIdx.y, t = blockIdx.z + 1;
  size_t o = ((size_t)t*BATCH + b)*VEXT + v;
  out[o] = __logf(out[o]);
}

extern "C" void kernel_launch(void* const* d_in, const int* in_sizes, int n_in,
                              void* d_out, int out_size, void* d_ws, size_t ws_size,
                              hipStream_t stream)
{
  (void)in_sizes; (void)n_in; (void)out_size; (void)ws_size;
  const int*   input_seq     = (const int*)d_in[0];
  const int*   input_seq_ext = (const int*)d_in[1];
  const int*   target_seq    = (const int*)d_in[2];
  const float* embedding     = (const float*)d_in[3];
  const float* enc_Wih_f     = (const float*)d_in[4];
  const float* enc_Whh_f     = (const float*)d_in[5];
  const float* enc_bih_f     = (const float*)d_in[6];
  const float* enc_bhh_f     = (const float*)d_in[7];
  const float* enc_Wih_b     = (const float*)d_in[8];
  const float* enc_Whh_b     = (const float*)d_in[9];
  const float* enc_bih_b     = (const float*)d_in[10];
  const float* enc_bhh_b     = (const float*)d_in[11];
  const float* proj_W        = (const float*)d_in[12];
  const float* proj_b        = (const float*)d_in[13];
  const float* bridge_W      = (const float*)d_in[14];
  const float* bridge_b      = (const float*)d_in[15];
  const float* dec_Wih       = (const float*)d_in[16];
  const float* dec_Whh       = (const float*)d_in[17];
  const float* dec_bih       = (const float*)d_in[18];
  const float* dec_bhh       = (const float*)d_in[19];
  const float* attn_Wq       = (const float*)d_in[20];
  const float* attn_We       = (const float*)d_in[21];
  const float* lin_W         = (const float*)d_in[22];
  const float* lin_b         = (const float*)d_in[23];
  const float* pgen_W        = (const float*)d_in[24];
  const float* pgen_b        = (const float*)d_in[25];
  const float* out_W         = (const float*)d_in[26];
  const float* out_b         = (const float*)d_in[27];
  float* out = (float*)d_out;
  float* ws  = (float*)d_ws;

  // workspace layout (floats); logits overlaps dead gi_f/gi_b region
  float* emb_src    = ws;                    // 1,638,400
  float* enc_states = ws + 1638400;          // 6,553,600
  float* proj       = ws + 8192000;          // 3,276,800
  float* gi_f       = ws + 11468800;         // 9,830,400
  float* gi_b       = ws + 11468800 + 9830400;
  float* logits     = ws + 11468800;         // 24,000,000 (reuses gi region)
  float* cat_all    = ws + 35468800;         // 480*896
  float* gie_all    = ws + 35898880;         // 480*768
  float* h_dec      = ws + 36267520;         // 32*256
  float* alphas     = ws + 36275712;         // 15*400*32
  float* lin_out    = ws + 36467712;         // 480*256
  float* pgen_all   = ws + 36590592;         // 480
  float* row_max    = ws + 36591072;         // 480
  float* row_sum    = ws + 36591552;         // 480
  // total ≈ 146.4 MB

  k_embed<<<dim3(SLEN*BATCH + NDEC*BATCH), dim3(64), 0, stream>>>(
      input_seq, target_seq, embedding, emb_src, cat_all);

  // gi = emb @ Wih.T + bih, both directions (backward uses reversed source rows)
  k_gemm<<<dim3(6,100), dim3(256), 0, stream>>>(emb_src, EDIM, enc_Wih_f, EDIM, enc_bih_f, gi_f, H3, SLEN*BATCH, H3, EDIM, 0);
  k_gemm<<<dim3(6,100), dim3(256), 0, stream>>>(emb_src, EDIM, enc_Wih_b, EDIM, enc_bih_b, gi_b, H3, SLEN*BATCH, H3, EDIM, 1);

  k_enc<<<dim3(64), dim3(1024), 0, stream>>>(gi_f, gi_b, enc_Whh_f, enc_bhh_f, enc_Whh_b, enc_bhh_b, enc_states);

  // proj = enc_states @ proj_W.T + proj_b
  k_gemm<<<dim3(2,100), dim3(256), 0, stream>>>(enc_states, 2*HDIM, proj_W, 2*HDIM, proj_b, proj, HDIM, SLEN*BATCH, HDIM, 2*HDIM, 0);

  k_bridge<<<dim3(BATCH), dim3(256), 0, stream>>>(enc_states, bridge_W, bridge_b, h_dec);

  // decoder-embedding part of GRU input gates (incl. dec_bih), batched over all t
  k_gemm<<<dim3(6,4), dim3(256), 0, stream>>>(cat_all, 896, dec_Wih, 640, dec_bih, gie_all, H3, NDEC*BATCH, H3, EDIM, 0);

  for (int t=0;t<NDEC;++t)
    k_dec_step<<<dim3(BATCH), dim3(256), 0, stream>>>(t, proj, enc_states, attn_Wq, attn_We,
        dec_Wih, dec_Whh, dec_bhh, gie_all, h_dec, alphas, cat_all);

  // batched epilogue over all 15 steps
  k_gemm<<<dim3(2,4), dim3(256), 0, stream>>>(cat_all, 896, lin_W, 896, lin_b, lin_out, HDIM, NDEC*BATCH, HDIM, 896, 0);
  k_pgen<<<dim3(NDEC*BATCH), dim3(64), 0, stream>>>(cat_all, pgen_W, pgen_b, pgen_all);
  k_gemm<<<dim3(391,4), dim3(256), 0, stream>>>(lin_out, HDIM, out_W, HDIM, out_b, logits, VVOC, NDEC*BATCH, VVOC, HDIM, 0);
  k_rowred<<<dim3(NDEC*BATCH), dim3(256), 0, stream>>>(logits, row_max, row_sum);
  k_final<<<dim3(196, BATCH, TLEN), dim3(256), 0, stream>>>(logits, pgen_all, row_max, row_sum, out);
  k_scatter<<<dim3(NDEC*BATCH), dim3(512), 0, stream>>>(input_seq_ext, alphas, pgen_all, out);
  k_log<<<dim3(196, BATCH, NDEC), dim3(256), 0, stream>>>(out);
}

// Round 4
// 3185.702 us; speedup vs baseline: 2.1344x; 2.1344x over previous
//
#include <hip/hip_runtime.h>

#define SLEN 400
#define BATCH 32
#define TLEN 16
#define NDEC 15
#define EDIM 128
#define HDIM 256
#define H3 768
#define VVOC 50000
#define VEXT 50020

// ---------- fast math helpers ----------
__device__ __forceinline__ float frcp(float x){ return __builtin_amdgcn_rcpf(x); }
__device__ __forceinline__ float fsig(float x){ return frcp(1.f + __expf(-x)); }
__device__ __forceinline__ float ftanh(float x){
  float e = __expf(2.f*x);
  return 1.f - 2.f*frcp(e + 1.f);
}

typedef _Float16 h2 __attribute__((ext_vector_type(2)));

__device__ __forceinline__ h2 u2h(unsigned u){ return __builtin_bit_cast(h2, u); }
__device__ __forceinline__ unsigned pkh(float a, float b){
  h2 v; v.x=(_Float16)a; v.y=(_Float16)b;
  return __builtin_bit_cast(unsigned, v);
}

#if __has_builtin(__builtin_amdgcn_fdot2)
__device__ __forceinline__ float fdot2h(h2 a, h2 b, float c){
  return __builtin_amdgcn_fdot2(a, b, c, false);
}
#else
__device__ __forceinline__ float fdot2h(h2 a, h2 b, float c){
  return fmaf((float)a.x,(float)b.x, fmaf((float)a.y,(float)b.y, c));
}
#endif

__device__ __forceinline__ float wred_max(float v){
  #pragma unroll
  for (int o=32;o>0;o>>=1) v = fmaxf(v, __shfl_down(v,o,64));
  return v;
}
__device__ __forceinline__ float wred_sum(float v){
  #pragma unroll
  for (int o=32;o>0;o>>=1) v += __shfl_down(v,o,64);
  return v;
}
__device__ __forceinline__ float block_max(float v, float* red){
  v = wred_max(v);
  int lane = threadIdx.x & 63, wid = threadIdx.x >> 6;
  if (!lane) red[wid] = v;
  __syncthreads();
  if (threadIdx.x == 0){
    float m = red[0];
    int nw = blockDim.x >> 6;
    for (int w=1;w<nw;++w) m = fmaxf(m, red[w]);
    red[0] = m;
  }
  __syncthreads();
  v = red[0];
  __syncthreads();
  return v;
}
__device__ __forceinline__ float block_sum(float v, float* red){
  v = wred_sum(v);
  int lane = threadIdx.x & 63, wid = threadIdx.x >> 6;
  if (!lane) red[wid] = v;
  __syncthreads();
  if (threadIdx.x == 0){
    float m = red[0];
    int nw = blockDim.x >> 6;
    for (int w=1;w<nw;++w) m += red[w];
    red[0] = m;
  }
  __syncthreads();
  v = red[0];
  __syncthreads();
  return v;
}

// ---------- embedding gather: src sequence (S,B,E) + decoder tokens into cat_all[:,0:128] ----------
__global__ __launch_bounds__(64) void k_embed(
    const int* __restrict__ input_seq, const int* __restrict__ target_seq,
    const float* __restrict__ embedding,
    float* __restrict__ emb_src, float* __restrict__ cat_all)
{
  int row = blockIdx.x;
  int tok; float* dst;
  if (row < SLEN*BATCH) {
    int s = row >> 5, b = row & 31;
    tok = input_seq[b*SLEN + s];
    dst = emb_src + (size_t)row*EDIM;
  } else {
    int rr = row - SLEN*BATCH;
    int t = rr >> 5, b = rr & 31;
    tok = target_seq[b*TLEN + t];       // toks = target_seq[:, :T-1].T
    dst = cat_all + (size_t)rr*896;     // cat cols [0:128) = e
  }
  const float2* src = (const float2*)(embedding + (size_t)tok*EDIM);
  ((float2*)dst)[threadIdx.x] = src[threadIdx.x];
}

// ---------- convert Whh (768x256 fp32, row-major) to f16, k-major uint4[32][768] ----------
// D[k8][jj] holds halves k8*8..k8*8+7 of row jj -> lane jj loads are coalesced 16B.
__global__ __launch_bounds__(32) void k_cvt(
    const float* __restrict__ W, uint4* __restrict__ D)
{
  int jj = blockIdx.x;          // 0..767
  int k8 = threadIdx.x;         // 0..31
  const float* s = W + (size_t)jj*HDIM + k8*8;
  float4 x = *(const float4*)s;
  float4 y = *(const float4*)(s+4);
  uint4 o;
  o.x = pkh(x.x,x.y); o.y = pkh(x.z,x.w);
  o.z = pkh(y.x,y.y); o.w = pkh(y.z,y.w);
  D[k8*H3 + jj] = o;
}

// ---------- encoder GRU recurrence: stream f16 weights from L2, v_dot2 accumulate ----------
// block = (dir, b), 768 threads. Thread jj owns gate-output jj (full K=256 dot).
// No register persistence (rounds 2/3: 768KB/block cannot fit VGPR file -> spill).
// Weights stream from per-XCD L2 (384KB f16/dir, resident) every step.
__global__ __launch_bounds__(768) void k_enc(
    const float* __restrict__ gi_f, const float* __restrict__ gi_b,
    const uint4* __restrict__ W16_f, const uint4* __restrict__ W16_b,
    const float* __restrict__ bhh_f, const float* __restrict__ bhh_b,
    float* __restrict__ enc_states)
{
  int dir = blockIdx.x >> 5, b = blockIdx.x & 31;
  int jj = threadIdx.x;                // 0..767
  const float* gi  = dir ? gi_b  : gi_f;
  const uint4* Wp  = (dir ? W16_b : W16_f) + jj;
  float bh = (dir ? bhh_b : bhh_f)[jj];

  __shared__ float    h_f[HDIM];       // fp32 master h
  __shared__ unsigned hpk[HDIM/2];     // packed f16 pairs of h
  __shared__ float    st[H3];          // staging: r,z pre-act / hn-dot

  if (jj < HDIM)   h_f[jj] = 0.f;
  if (jj < HDIM/2) hpk[jj] = 0u;
  float* dst = enc_states + (size_t)b*2*HDIM + dir*HDIM + jj;   // valid for jj<256 use
  __syncthreads();

  for (int s=0;s<SLEN;++s){
    const float* grow = gi + ((size_t)s*BATCH + b)*H3;
    float ac0=0.f, ac1=0.f, ac2=0.f, ac3=0.f;
    #pragma unroll
    for (int k8=0;k8<32;k8+=4){
      uint4 w0 = Wp[(k8+0)*H3];
      uint4 w1 = Wp[(k8+1)*H3];
      uint4 w2 = Wp[(k8+2)*H3];
      uint4 w3 = Wp[(k8+3)*H3];
      uint4 p0 = *(const uint4*)&hpk[(k8+0)*4];
      uint4 p1 = *(const uint4*)&hpk[(k8+1)*4];
      uint4 p2 = *(const uint4*)&hpk[(k8+2)*4];
      uint4 p3 = *(const uint4*)&hpk[(k8+3)*4];
      ac0 = fdot2h(u2h(w0.x),u2h(p0.x), ac0); ac0 = fdot2h(u2h(w0.y),u2h(p0.y), ac0);
      ac0 = fdot2h(u2h(w0.z),u2h(p0.z), ac0); ac0 = fdot2h(u2h(w0.w),u2h(p0.w), ac0);
      ac1 = fdot2h(u2h(w1.x),u2h(p1.x), ac1); ac1 = fdot2h(u2h(w1.y),u2h(p1.y), ac1);
      ac1 = fdot2h(u2h(w1.z),u2h(p1.z), ac1); ac1 = fdot2h(u2h(w1.w),u2h(p1.w), ac1);
      ac2 = fdot2h(u2h(w2.x),u2h(p2.x), ac2); ac2 = fdot2h(u2h(w2.y),u2h(p2.y), ac2);
      ac2 = fdot2h(u2h(w2.z),u2h(p2.z), ac2); ac2 = fdot2h(u2h(w2.w),u2h(p2.w), ac2);
      ac3 = fdot2h(u2h(w3.x),u2h(p3.x), ac3); ac3 = fdot2h(u2h(w3.y),u2h(p3.y), ac3);
      ac3 = fdot2h(u2h(w3.z),u2h(p3.z), ac3); ac3 = fdot2h(u2h(w3.w),u2h(p3.w), ac3);
    }
    float acc = (ac0+ac1)+(ac2+ac3) + bh;
    // r,z rows get gi added now; n row keeps dot+bias only (gi_n added after r*hn)
    st[jj] = (jj < 512) ? (acc + grow[jj]) : acc;
    __syncthreads();
    if (jj < HDIM){
      float hp = h_f[jj];
      float rr = fsig(st[jj]);
      float zz = fsig(st[HDIM + jj]);
      float nn = ftanh(grow[2*HDIM + jj] + rr*st[2*HDIM + jj]);
      float h2 = nn + zz*(hp - nn);          // (1-z)*n + z*h
      h_f[jj] = h2;
      int srow = dir ? (SLEN-1-s) : s;
      dst[(size_t)srow*BATCH*2*HDIM] = h2;
      ((_Float16*)hpk)[jj] = (_Float16)h2;   // packed copy for next step's dot2
    }
    __syncthreads();
  }
}

// ---------- generic tiled GEMM: C[m,n] = sum_k A[am,k]*W[n,k] + bias[n] ----------
// rev=1 remaps A row m=(s*32+b) -> ((S-1-s)*32+b)   (for backward-direction gi)
#define GBM 128
#define GBN 128
#define GBK 32
__global__ __launch_bounds__(256) void k_gemm(
    const float* __restrict__ A, int lda,
    const float* __restrict__ W, int ldw,
    const float* __restrict__ bias,
    float* __restrict__ C, int ldc,
    int M, int N, int K, int rev)
{
  __shared__ float As[GBK][GBM+4];
  __shared__ float Ws[GBK][GBN+4];
  int tid = threadIdx.x;
  int ty = tid >> 4, tx = tid & 15;
  int m0 = blockIdx.y*GBM, n0 = blockIdx.x*GBN;
  float acc[8][8];
  #pragma unroll
  for (int i=0;i<8;++i)
    #pragma unroll
    for (int jj=0;jj<8;++jj) acc[i][jj] = 0.f;

  for (int k0=0;k0<K;k0+=GBK){
    #pragma unroll
    for (int i=0;i<4;++i){
      int idx = tid + i*256;
      int row = idx >> 3, c4 = idx & 7;
      int m = m0 + row, k = k0 + c4*4;
      float4 v = {0.f,0.f,0.f,0.f};
      if (m < M){
        int am = m;
        if (rev){ int s = m >> 5; am = ((SLEN-1-s)<<5) | (m&31); }
        v = *(const float4*)&A[(size_t)am*lda + k];
      }
      As[c4*4+0][row]=v.x; As[c4*4+1][row]=v.y; As[c4*4+2][row]=v.z; As[c4*4+3][row]=v.w;
    }
    #pragma unroll
    for (int i=0;i<4;++i){
      int idx = tid + i*256;
      int row = idx >> 3, c4 = idx & 7;
      int n = n0 + row, k = k0 + c4*4;
      float4 v = {0.f,0.f,0.f,0.f};
      if (n < N) v = *(const float4*)&W[(size_t)n*ldw + k];
      Ws[c4*4+0][row]=v.x; Ws[c4*4+1][row]=v.y; Ws[c4*4+2][row]=v.z; Ws[c4*4+3][row]=v.w;
    }
    __syncthreads();
    #pragma unroll 4
    for (int kk=0;kk<GBK;++kk){
      float4 a0 = *(const float4*)&As[kk][ty*8];
      float4 a1 = *(const float4*)&As[kk][ty*8+4];
      float4 b0 = *(const float4*)&Ws[kk][tx*8];
      float4 b1 = *(const float4*)&Ws[kk][tx*8+4];
      float av[8]={a0.x,a0.y,a0.z,a0.w,a1.x,a1.y,a1.z,a1.w};
      float bv[8]={b0.x,b0.y,b0.z,b0.w,b1.x,b1.y,b1.z,b1.w};
      #pragma unroll
      for (int i=0;i<8;++i)
        #pragma unroll
        for (int jj=0;jj<8;++jj) acc[i][jj]=fmaf(av[i],bv[jj],acc[i][jj]);
    }
    __syncthreads();
  }
  #pragma unroll
  for (int i=0;i<8;++i){
    int m = m0 + ty*8 + i;
    if (m < M){
      #pragma unroll
      for (int jj=0;jj<8;++jj){
        int n = n0 + tx*8 + jj;
        if (n < N) C[(size_t)m*ldc + n] = acc[i][jj] + bias[n];
      }
    }
  }
}

// ---------- bridge: h0 = tanh([hf,hb] @ bridge_W.T + b) ----------
__global__ __launch_bounds__(256) void k_bridge(
    const float* __restrict__ enc_states,
    const float* __restrict__ bridge_W, const float* __restrict__ bridge_b,
    float* __restrict__ h_dec)
{
  int b = blockIdx.x, j = threadIdx.x;
  __shared__ float hcat[2*HDIM];
  hcat[j]        = enc_states[((size_t)(SLEN-1)*BATCH + b)*2*HDIM + j];          // forward final
  hcat[HDIM + j] = enc_states[(size_t)b*2*HDIM + HDIM + j];                      // backward final (s=0 slot)
  __syncthreads();
  const float* w = bridge_W + (size_t)j*2*HDIM;
  float4 a = {0.f,0.f,0.f,0.f};
  #pragma unroll 4
  for (int k=0;k<2*HDIM;k+=4){
    float4 h4 = *(const float4*)&hcat[k];
    float4 w4 = *(const float4*)&w[k];
    a.x=fmaf(h4.x,w4.x,a.x); a.y=fmaf(h4.y,w4.y,a.y);
    a.z=fmaf(h4.z,w4.z,a.z); a.w=fmaf(h4.w,w4.w,a.w);
  }
  h_dec[b*HDIM+j] = ftanh((a.x+a.y)+(a.z+a.w) + bridge_b[j]);
}

// ---------- one decoder step: attention + context + GRU (block = batch row) ----------
__global__ __launch_bounds__(256) void k_dec_step(
    int t,
    const float* __restrict__ proj,
    const float* __restrict__ enc_states,
    const float* __restrict__ attn_Wq,
    const float* __restrict__ attn_We,
    const float* __restrict__ dec_Wih,
    const float* __restrict__ dec_Whh,
    const float* __restrict__ dec_bhh,
    const float* __restrict__ gie_all,
    float* __restrict__ h_dec,
    float* __restrict__ alphas_all,
    float* __restrict__ cat_all)
{
  int b = blockIdx.x, j = threadIdx.x;
  __shared__ float h_s[HDIM], q_s[HDIM], we_s[HDIM], ctx_s[2*HDIM], sc[SLEN];
  __shared__ float red[8];
  h_s[j] = h_dec[b*HDIM + j];
  we_s[j] = attn_We[j];
  __syncthreads();
  // q = h @ Wq.T
  {
    const float* wq = attn_Wq + (size_t)j*HDIM;
    float4 a = {0.f,0.f,0.f,0.f};
    #pragma unroll 8
    for (int k=0;k<HDIM;k+=4){
      float4 h4 = *(const float4*)&h_s[k];
      float4 w4 = *(const float4*)&wq[k];
      a.x=fmaf(h4.x,w4.x,a.x); a.y=fmaf(h4.y,w4.y,a.y);
      a.z=fmaf(h4.z,w4.z,a.z); a.w=fmaf(h4.w,w4.w,a.w);
    }
    q_s[j] = (a.x+a.y)+(a.z+a.w);
  }
  __syncthreads();
  // scores[s] = tanh(q + proj[s,b]) . We
  for (int s=j; s<SLEN; s+=256){
    const float* pr = proj + ((size_t)s*BATCH + b)*HDIM;
    float4 a = {0.f,0.f,0.f,0.f};
    #pragma unroll 4
    for (int k=0;k<HDIM;k+=4){
      float4 p4 = *(const float4*)&pr[k];
      float4 q4 = *(const float4*)&q_s[k];
      float4 w4 = *(const float4*)&we_s[k];
      a.x = fmaf(ftanh(q4.x+p4.x), w4.x, a.x);
      a.y = fmaf(ftanh(q4.y+p4.y), w4.y, a.y);
      a.z = fmaf(ftanh(q4.z+p4.z), w4.z, a.z);
      a.w = fmaf(ftanh(q4.w+p4.w), w4.w, a.w);
    }
    sc[s] = (a.x+a.y)+(a.z+a.w);
  }
  __syncthreads();
  // softmax over s
  float m = -1e30f;
  for (int s=j; s<SLEN; s+=256) m = fmaxf(m, sc[s]);
  m = block_max(m, red);
  float ssum = 0.f;
  for (int s=j; s<SLEN; s+=256){ float e = __expf(sc[s]-m); sc[s]=e; ssum+=e; }
  ssum = block_sum(ssum, red);
  float inv = 1.f/ssum;
  for (int s=j; s<SLEN; s+=256){
    float a = sc[s]*inv; sc[s]=a;
    alphas_all[((size_t)t*SLEN + s)*BATCH + b] = a;
  }
  __syncthreads();
  int r = t*BATCH + b;
  // context = sum_s alpha[s] * enc_states[s,b,:]
  for (int d=j; d<2*HDIM; d+=256){
    const float* e0 = enc_states + (size_t)b*2*HDIM + d;
    float a0=0.f,a1=0.f,a2=0.f,a3=0.f;
    #pragma unroll 4
    for (int s=0;s<SLEN;s+=4){
      a0 = fmaf(sc[s+0], e0[(size_t)(s+0)*BATCH*2*HDIM], a0);
      a1 = fmaf(sc[s+1], e0[(size_t)(s+1)*BATCH*2*HDIM], a1);
      a2 = fmaf(sc[s+2], e0[(size_t)(s+2)*BATCH*2*HDIM], a2);
      a3 = fmaf(sc[s+3], e0[(size_t)(s+3)*BATCH*2*HDIM], a3);
    }
    float c = (a0+a1)+(a2+a3);
    ctx_s[d] = c;
    cat_all[(size_t)r*896 + 384 + d] = c;   // cat cols [384:896) = context
  }
  __syncthreads();
  // GRU cell: x = [e, context]; e-part (incl. bih) precomputed in gie_all
  float g[3], hh[3];
  #pragma unroll
  for (int gg=0; gg<3; ++gg){
    int jj = gg*HDIM + j;
    const float* wi = dec_Wih + (size_t)jj*640 + 128;   // ctx columns
    float4 a = {0.f,0.f,0.f,0.f};
    #pragma unroll 4
    for (int k=0;k<2*HDIM;k+=4){
      float4 c4 = *(const float4*)&ctx_s[k];
      float4 w4 = *(const float4*)&wi[k];
      a.x=fmaf(c4.x,w4.x,a.x); a.y=fmaf(c4.y,w4.y,a.y);
      a.z=fmaf(c4.z,w4.z,a.z); a.w=fmaf(c4.w,w4.w,a.w);
    }
    g[gg] = gie_all[(size_t)r*H3 + jj] + (a.x+a.y)+(a.z+a.w);
    const float* wh = dec_Whh + (size_t)jj*HDIM;
    float4 h4a = {0.f,0.f,0.f,0.f};
    #pragma unroll 4
    for (int k=0;k<HDIM;k+=4){
      float4 h4 = *(const float4*)&h_s[k];
      float4 w4 = *(const float4*)&wh[k];
      h4a.x=fmaf(h4.x,w4.x,h4a.x); h4a.y=fmaf(h4.y,w4.y,h4a.y);
      h4a.z=fmaf(h4.z,w4.z,h4a.z); h4a.w=fmaf(h4.w,w4.w,h4a.w);
    }
    hh[gg] = dec_bhh[jj] + (h4a.x+h4a.y)+(h4a.z+h4a.w);
  }
  float rr = fsig(g[0]+hh[0]);
  float zz = fsig(g[1]+hh[1]);
  float nn = ftanh(g[2] + rr*hh[2]);
  float h2 = nn + zz*(h_s[j]-nn);
  h_dec[b*HDIM + j] = h2;
  cat_all[(size_t)r*896 + 128 + j] = h2;    // cat cols [128:384) = h2
}

// ---------- p_gen = sigmoid(cat . pgen_W + b) ----------
__global__ __launch_bounds__(64) void k_pgen(
    const float* __restrict__ cat_all,
    const float* __restrict__ pgen_W, const float* __restrict__ pgen_b,
    float* __restrict__ pgen_all)
{
  int r = blockIdx.x;
  const float* c = cat_all + (size_t)r*896;
  float acc = 0.f;
  for (int k=threadIdx.x; k<896; k+=64) acc = fmaf(c[k], pgen_W[k], acc);
  acc = wred_sum(acc);
  if (threadIdx.x==0) pgen_all[r] = fsig(acc + pgen_b[0]);
}

// ---------- per-row softmax stats over V ----------
__global__ __launch_bounds__(256) void k_rowred(
    const float* __restrict__ logits,
    float* __restrict__ row_max, float* __restrict__ row_sum)
{
  int r = blockIdx.x;
  const float4* row = (const float4*)(logits + (size_t)r*VVOC);
  __shared__ float red[8];
  float m = -1e30f;
  for (int v=threadIdx.x; v<VVOC/4; v+=256){
    float4 x = row[v];
    m = fmaxf(m, fmaxf(fmaxf(x.x,x.y), fmaxf(x.z,x.w)));
  }
  m = block_max(m, red);
  float s = 0.f;
  for (int v=threadIdx.x; v<VVOC/4; v+=256){
    float4 x = row[v];
    s += __expf(x.x-m) + __expf(x.y-m) + __expf(x.z-m) + __expf(x.w-m);
  }
  s = block_sum(s, red);
  if (threadIdx.x==0){ row_max[r]=m; row_sum[r]=1.f/s; }
}

// ---------- write ext (linear domain) for all (t,b,v); t=0 row = 0 ----------
__global__ __launch_bounds__(256) void k_final(
    const float* __restrict__ logits, const float* __restrict__ pgen_all,
    const float* __restrict__ row_max, const float* __restrict__ row_sum,
    float* __restrict__ out)
{
  int v = blockIdx.x*256 + threadIdx.x;
  if (v >= VEXT) return;
  int b = blockIdx.y, t = blockIdx.z;
  size_t o = ((size_t)t*BATCH + b)*VEXT + v;
  if (t == 0){ out[o] = 0.f; return; }
  int r = (t-1)*BATCH + b;
  float val = 1e-12f;
  if (v < VVOC)
    val += pgen_all[r] * row_sum[r] * __expf(logits[(size_t)r*VVOC + v] - row_max[r]);
  out[o] = val;
}

// ---------- scatter copy-distribution ----------
__global__ __launch_bounds__(512) void k_scatter(
    const int* __restrict__ input_seq_ext,
    const float* __restrict__ alphas, const float* __restrict__ pgen_all,
    float* __restrict__ out)
{
  int r = blockIdx.x;               // t*32+b
  int s = threadIdx.x;
  if (s >= SLEN) return;
  int t = r >> 5, b = r & 31;
  float w = (1.f - pgen_all[r]) * alphas[((size_t)t*SLEN + s)*BATCH + b];
  int idx = input_seq_ext[b*SLEN + s];
  atomicAdd(&out[((size_t)(t+1)*BATCH + b)*VEXT + idx], w);
}

// ---------- log transform rows t>=1 ----------
__global__ __launch_bounds__(256) void k_log(float* __restrict__ out)
{
  int v = blockIdx.x*256 + threadIdx.x;
  if (v >= VEXT) return;
  int b = blockIdx.y, t = blockIdx.z + 1;
  size_t o = ((size_t)t*BATCH + b)*VEXT + v;
  out[o] = __logf(out[o]);
}

extern "C" void kernel_launch(void* const* d_in, const int* in_sizes, int n_in,
                              void* d_out, int out_size, void* d_ws, size_t ws_size,
                              hipStream_t stream)
{
  (void)in_sizes; (void)n_in; (void)out_size; (void)ws_size;
  const int*   input_seq     = (const int*)d_in[0];
  const int*   input_seq_ext = (const int*)d_in[1];
  const int*   target_seq    = (const int*)d_in[2];
  const float* embedding     = (const float*)d_in[3];
  const float* enc_Wih_f     = (const float*)d_in[4];
  const float* enc_Whh_f     = (const float*)d_in[5];
  const float* enc_bih_f     = (const float*)d_in[6];
  const float* enc_bhh_f     = (const float*)d_in[7];
  const float* enc_Wih_b     = (const float*)d_in[8];
  const float* enc_Whh_b     = (const float*)d_in[9];
  const float* enc_bih_b     = (const float*)d_in[10];
  const float* enc_bhh_b     = (const float*)d_in[11];
  const float* proj_W        = (const float*)d_in[12];
  const float* proj_b        = (const float*)d_in[13];
  const float* bridge_W      = (const float*)d_in[14];
  const float* bridge_b      = (const float*)d_in[15];
  const float* dec_Wih       = (const float*)d_in[16];
  const float* dec_Whh       = (const float*)d_in[17];
  const float* dec_bih       = (const float*)d_in[18];
  const float* dec_bhh       = (const float*)d_in[19];
  const float* attn_Wq       = (const float*)d_in[20];
  const float* attn_We       = (const float*)d_in[21];
  const float* lin_W         = (const float*)d_in[22];
  const float* lin_b         = (const float*)d_in[23];
  const float* pgen_W        = (const float*)d_in[24];
  const float* pgen_b        = (const float*)d_in[25];
  const float* out_W         = (const float*)d_in[26];
  const float* out_b         = (const float*)d_in[27];
  float* out = (float*)d_out;
  float* ws  = (float*)d_ws;

  // workspace layout (floats); logits overlaps dead gi_f/gi_b region.
  // W16 (f16 enc weights) overlaps the TAIL of logits: written before k_enc,
  // consumed by k_enc, overwritten later by the logits GEMM. 196608 floats needed,
  // tail [35000000, 35468800) has 468800 -> safe, and rewritten every call.
  float* emb_src    = ws;                    // 1,638,400
  float* enc_states = ws + 1638400;          // 6,553,600
  float* proj       = ws + 8192000;          // 3,276,800
  float* gi_f       = ws + 11468800;         // 9,830,400
  float* gi_b       = ws + 11468800 + 9830400;
  float* logits     = ws + 11468800;         // 24,000,000 (reuses gi region)
  uint4* W16_f      = (uint4*)(ws + 35000000);          // 98,304 floats (as u32)
  uint4* W16_b      = (uint4*)(ws + 35000000 + 98304);  // 98,304 floats
  float* cat_all    = ws + 35468800;         // 480*896
  float* gie_all    = ws + 35898880;         // 480*768
  float* h_dec      = ws + 36267520;         // 32*256
  float* alphas     = ws + 36275712;         // 15*400*32
  float* lin_out    = ws + 36467712;         // 480*256
  float* pgen_all   = ws + 36590592;         // 480
  float* row_max    = ws + 36591072;         // 480
  float* row_sum    = ws + 36591552;         // 480
  // total ≈ 146.4 MB

  k_embed<<<dim3(SLEN*BATCH + NDEC*BATCH), dim3(64), 0, stream>>>(
      input_seq, target_seq, embedding, emb_src, cat_all);

  // f16 conversion of recurrent weights (k-major layout for coalesced streaming)
  k_cvt<<<dim3(H3), dim3(32), 0, stream>>>(enc_Whh_f, W16_f);
  k_cvt<<<dim3(H3), dim3(32), 0, stream>>>(enc_Whh_b, W16_b);

  // gi = emb @ Wih.T + bih, both directions (backward uses reversed source rows)
  k_gemm<<<dim3(6,100), dim3(256), 0, stream>>>(emb_src, EDIM, enc_Wih_f, EDIM, enc_bih_f, gi_f, H3, SLEN*BATCH, H3, EDIM, 0);
  k_gemm<<<dim3(6,100), dim3(256), 0, stream>>>(emb_src, EDIM, enc_Wih_b, EDIM, enc_bih_b, gi_b, H3, SLEN*BATCH, H3, EDIM, 1);

  k_enc<<<dim3(64), dim3(768), 0, stream>>>(gi_f, gi_b, W16_f, W16_b, enc_bhh_f, enc_bhh_b, enc_states);

  // proj = enc_states @ proj_W.T + proj_b
  k_gemm<<<dim3(2,100), dim3(256), 0, stream>>>(enc_states, 2*HDIM, proj_W, 2*HDIM, proj_b, proj, HDIM, SLEN*BATCH, HDIM, 2*HDIM, 0);

  k_bridge<<<dim3(BATCH), dim3(256), 0, stream>>>(enc_states, bridge_W, bridge_b, h_dec);

  // decoder-embedding part of GRU input gates (incl. dec_bih), batched over all t
  k_gemm<<<dim3(6,4), dim3(256), 0, stream>>>(cat_all, 896, dec_Wih, 640, dec_bih, gie_all, H3, NDEC*BATCH, H3, EDIM, 0);

  for (int t=0;t<NDEC;++t)
    k_dec_step<<<dim3(BATCH), dim3(256), 0, stream>>>(t, proj, enc_states, attn_Wq, attn_We,
        dec_Wih, dec_Whh, dec_bhh, gie_all, h_dec, alphas, cat_all);

  // batched epilogue over all 15 steps
  k_gemm<<<dim3(2,4), dim3(256), 0, stream>>>(cat_all, 896, lin_W, 896, lin_b, lin_out, HDIM, NDEC*BATCH, HDIM, 896, 0);
  k_pgen<<<dim3(NDEC*BATCH), dim3(64), 0, stream>>>(cat_all, pgen_W, pgen_b, pgen_all);
  k_gemm<<<dim3(391,4), dim3(256), 0, stream>>>(lin_out, HDIM, out_W, HDIM, out_b, logits, VVOC, NDEC*BATCH, VVOC, HDIM, 0);
  k_rowred<<<dim3(NDEC*BATCH), dim3(256), 0, stream>>>(logits, row_max, row_sum);
  k_final<<<dim3(196, BATCH, TLEN), dim3(256), 0, stream>>>(logits, pgen_all, row_max, row_sum, out);
  k_scatter<<<dim3(NDEC*BATCH), dim3(512), 0, stream>>>(input_seq_ext, alphas, pgen_all, out);
  k_log<<<dim3(196, BATCH, NDEC), dim3(256), 0, stream>>>(out);
}

// Round 5
// 2675.345 us; speedup vs baseline: 2.5416x; 1.1908x over previous
//
#include <hip/hip_runtime.h>

#define SLEN 400
#define BATCH 32
#define TLEN 16
#define NDEC 15
#define EDIM 128
#define HDIM 256
#define H3 768
#define VVOC 50000
#define VEXT 50020

// ---------- fast math helpers ----------
__device__ __forceinline__ float frcp(float x){ return __builtin_amdgcn_rcpf(x); }
__device__ __forceinline__ float fsig(float x){ return frcp(1.f + __expf(-x)); }
__device__ __forceinline__ float ftanh(float x){
  float e = __expf(2.f*x);
  return 1.f - 2.f*frcp(e + 1.f);
}

typedef _Float16 h2 __attribute__((ext_vector_type(2)));
typedef _Float16 half8 __attribute__((ext_vector_type(8)));
typedef float floatx4 __attribute__((ext_vector_type(4)));

__device__ __forceinline__ h2 u2h(unsigned u){ return __builtin_bit_cast(h2, u); }
__device__ __forceinline__ unsigned pkh(float a, float b){
  h2 v; v.x=(_Float16)a; v.y=(_Float16)b;
  return __builtin_bit_cast(unsigned, v);
}

#if __has_builtin(__builtin_amdgcn_fdot2)
__device__ __forceinline__ float fdot2h(h2 a, h2 b, float c){
  return __builtin_amdgcn_fdot2(a, b, c, false);
}
#else
__device__ __forceinline__ float fdot2h(h2 a, h2 b, float c){
  return fmaf((float)a.x,(float)b.x, fmaf((float)a.y,(float)b.y, c));
}
#endif

__device__ __forceinline__ float wred_max(float v){
  #pragma unroll
  for (int o=32;o>0;o>>=1) v = fmaxf(v, __shfl_down(v,o,64));
  return v;
}
__device__ __forceinline__ float wred_sum(float v){
  #pragma unroll
  for (int o=32;o>0;o>>=1) v += __shfl_down(v,o,64);
  return v;
}
__device__ __forceinline__ float block_max(float v, float* red){
  v = wred_max(v);
  int lane = threadIdx.x & 63, wid = threadIdx.x >> 6;
  if (!lane) red[wid] = v;
  __syncthreads();
  if (threadIdx.x == 0){
    float m = red[0];
    int nw = blockDim.x >> 6;
    for (int w=1;w<nw;++w) m = fmaxf(m, red[w]);
    red[0] = m;
  }
  __syncthreads();
  v = red[0];
  __syncthreads();
  return v;
}
__device__ __forceinline__ float block_sum(float v, float* red){
  v = wred_sum(v);
  int lane = threadIdx.x & 63, wid = threadIdx.x >> 6;
  if (!lane) red[wid] = v;
  __syncthreads();
  if (threadIdx.x == 0){
    float m = red[0];
    int nw = blockDim.x >> 6;
    for (int w=1;w<nw;++w) m += red[w];
    red[0] = m;
  }
  __syncthreads();
  v = red[0];
  __syncthreads();
  return v;
}

// ---------- embedding gather: emb16 (f16) + decoder token rows into cat (fp32+f16) ----------
__global__ __launch_bounds__(64) void k_embed(
    const int* __restrict__ input_seq, const int* __restrict__ target_seq,
    const float* __restrict__ embedding,
    _Float16* __restrict__ emb16, float* __restrict__ cat_all, _Float16* __restrict__ cat16)
{
  int row = blockIdx.x;
  if (row < SLEN*BATCH) {
    int s = row >> 5, b = row & 31;
    int tok = input_seq[b*SLEN + s];
    float2 v = ((const float2*)(embedding + (size_t)tok*EDIM))[threadIdx.x];
    ((unsigned*)(emb16 + (size_t)row*EDIM))[threadIdx.x] = pkh(v.x, v.y);
  } else {
    int rr = row - SLEN*BATCH;
    int t = rr >> 5, b = rr & 31;
    int tok = target_seq[b*TLEN + t];       // toks = target_seq[:, :T-1].T
    float2 v = ((const float2*)(embedding + (size_t)tok*EDIM))[threadIdx.x];
    ((float2*)(cat_all + (size_t)rr*896))[threadIdx.x] = v;       // cat cols [0:128) = e
    ((unsigned*)(cat16 + (size_t)rr*896))[threadIdx.x] = pkh(v.x, v.y);
  }
}

// ---------- flat fp32 -> f16 convert (8 elems/thread) ----------
__global__ __launch_bounds__(256) void k_cvtv(
    const float* __restrict__ S, _Float16* __restrict__ D, int n8)
{
  int i = blockIdx.x*256 + threadIdx.x;
  if (i >= n8) return;
  float4 a = ((const float4*)S)[i*2];
  float4 b = ((const float4*)S)[i*2+1];
  uint4 o;
  o.x = pkh(a.x,a.y); o.y = pkh(a.z,a.w);
  o.z = pkh(b.x,b.y); o.w = pkh(b.z,b.w);
  ((uint4*)D)[i] = o;
}

// ---------- convert Whh (768x256 fp32) to f16, k-major uint4[32][768] (for k_enc) ----------
__global__ __launch_bounds__(32) void k_cvt(
    const float* __restrict__ W, uint4* __restrict__ D)
{
  int jj = blockIdx.x;          // 0..767
  int k8 = threadIdx.x;         // 0..31
  const float* s = W + (size_t)jj*HDIM + k8*8;
  float4 x = *(const float4*)s;
  float4 y = *(const float4*)(s+4);
  uint4 o;
  o.x = pkh(x.x,x.y); o.y = pkh(x.z,x.w);
  o.z = pkh(y.x,y.y); o.w = pkh(y.z,y.w);
  D[k8*H3 + jj] = o;
}

// ---------- MFMA f16 GEMM: C[m,n] = sum_k A16[am,k]*W16[n,k] + bias[n] ----------
// A16: MxK halves row-major (lda halves); W16: NxK halves (ldw halves).
// C fp32 (optional), C16 f16 (optional), ldc elems. rev: s-reverse A rows.
// 128x128 tile, BK=64 halves, 4 waves each 64x64 via 16 mfma_f32_16x16x32_f16 / ksub.
// LDS XOR-swizzle (chunk ^= row&7) kills the 128B-row-stride bank conflict (G4).
__global__ __launch_bounds__(256) void k_gmm(
    const _Float16* __restrict__ A, int lda,
    const _Float16* __restrict__ W, int ldw,
    const float* __restrict__ bias,
    float* __restrict__ C, _Float16* __restrict__ C16, int ldc,
    int M, int N, int K, int rev)
{
  __shared__ __align__(16) _Float16 Al[128*64];
  __shared__ __align__(16) _Float16 Wl[128*64];
  int tid = threadIdx.x;
  int wv = tid >> 6, l = tid & 63;
  int wr = (wv>>1)*64, wc = (wv&1)*64;
  int lr = l & 15, lh = l >> 4;
  int m0 = blockIdx.y*128, n0 = blockIdx.x*128;
  floatx4 acc[4][4];
  #pragma unroll
  for (int i=0;i<4;++i)
    #pragma unroll
    for (int jn=0;jn<4;++jn) acc[i][jn] = (floatx4){0.f,0.f,0.f,0.f};

  for (int kc=0; kc<K; kc+=64){
    #pragma unroll
    for (int i=0;i<4;++i){
      int idx = tid + i*256;
      int row = idx>>3, c = idx&7;
      int m = m0+row;
      uint4 v = {0u,0u,0u,0u};
      if (m < M){
        int am = m;
        if (rev){ int s = m>>5; am = ((SLEN-1-s)<<5)|(m&31); }
        v = *(const uint4*)&A[(size_t)am*lda + kc + c*8];
      }
      *(uint4*)&Al[row*64 + ((c ^ (row&7))<<3)] = v;
    }
    #pragma unroll
    for (int i=0;i<4;++i){
      int idx = tid + i*256;
      int row = idx>>3, c = idx&7;
      int n = n0+row;
      uint4 v = {0u,0u,0u,0u};
      if (n < N) v = *(const uint4*)&W[(size_t)n*ldw + kc + c*8];
      *(uint4*)&Wl[row*64 + ((c ^ (row&7))<<3)] = v;
    }
    __syncthreads();
    #pragma unroll
    for (int ks=0; ks<2; ++ks){
      half8 af0, af1, af2, af3, bf0, bf1, bf2, bf3;
      {
        int c = ks*4 + lh;
        int r0 = wr + 0*16 + lr, r1 = wr + 1*16 + lr, r2 = wr + 2*16 + lr, r3 = wr + 3*16 + lr;
        af0 = *(const half8*)&Al[r0*64 + ((c ^ (r0&7))<<3)];
        af1 = *(const half8*)&Al[r1*64 + ((c ^ (r1&7))<<3)];
        af2 = *(const half8*)&Al[r2*64 + ((c ^ (r2&7))<<3)];
        af3 = *(const half8*)&Al[r3*64 + ((c ^ (r3&7))<<3)];
        int n0l = wc + 0*16 + lr, n1l = wc + 1*16 + lr, n2l = wc + 2*16 + lr, n3l = wc + 3*16 + lr;
        bf0 = *(const half8*)&Wl[n0l*64 + ((c ^ (n0l&7))<<3)];
        bf1 = *(const half8*)&Wl[n1l*64 + ((c ^ (n1l&7))<<3)];
        bf2 = *(const half8*)&Wl[n2l*64 + ((c ^ (n2l&7))<<3)];
        bf3 = *(const half8*)&Wl[n3l*64 + ((c ^ (n3l&7))<<3)];
      }
      half8 afs[4] = {af0, af1, af2, af3};
      half8 bfs[4] = {bf0, bf1, bf2, bf3};
      #pragma unroll
      for (int mi=0;mi<4;++mi)
        #pragma unroll
        for (int ni=0;ni<4;++ni)
          acc[mi][ni] = __builtin_amdgcn_mfma_f32_16x16x32_f16(afs[mi], bfs[ni], acc[mi][ni], 0,0,0);
    }
    __syncthreads();
  }
  #pragma unroll
  for (int mi=0;mi<4;++mi){
    #pragma unroll
    for (int q=0;q<4;++q){
      int m = m0 + wr + mi*16 + lh*4 + q;
      if (m < M){
        #pragma unroll
        for (int ni=0;ni<4;++ni){
          int n = n0 + wc + ni*16 + lr;
          if (n < N){
            float v = acc[mi][ni][q] + bias[n];
            if (C)   C[(size_t)m*ldc + n] = v;
            if (C16) C16[(size_t)m*ldc + n] = (_Float16)v;
          }
        }
      }
    }
  }
}

// ---------- encoder GRU recurrence: 12/32 weight chunks LDS-cached, 20 streamed from L2 ----------
// block = (dir, b), 768 threads. Thread jj owns gate-output jj (full K=256 dot).
// The 20 L2 chunks are NAMED uint4 regs issued up-front -> all loads in flight together.
#define L20(M) M(12) M(13) M(14) M(15) M(16) M(17) M(18) M(19) M(20) M(21) \
               M(22) M(23) M(24) M(25) M(26) M(27) M(28) M(29) M(30) M(31)

__global__ __launch_bounds__(768) void k_enc(
    const float* __restrict__ gi_f, const float* __restrict__ gi_b,
    const uint4* __restrict__ W16_f, const uint4* __restrict__ W16_b,
    const float* __restrict__ bhh_f, const float* __restrict__ bhh_b,
    float* __restrict__ enc_states)
{
  int dir = blockIdx.x >> 5, b = blockIdx.x & 31;
  int jj = threadIdx.x;
  const float* gi  = dir ? gi_b  : gi_f;
  const uint4* Wp  = (dir ? W16_b : W16_f) + jj;
  float bh = (dir ? bhh_b : bhh_f)[jj];

  __shared__ __align__(16) unsigned hpk[HDIM/2];   // packed f16 h
  __shared__ __align__(16) float st[H3];           // gate staging
  __shared__ uint4 Wlds[12][H3];                   // 147456 B cached weight chunks

  #pragma unroll
  for (int k8=0;k8<12;++k8) Wlds[k8][jj] = Wp[k8*H3];

  if (jj < HDIM/2) hpk[jj] = 0u;
  float hreg = 0.f;                                // h[jj] register (jj<256 meaningful)
  float* dst = enc_states + (size_t)b*2*HDIM + dir*HDIM + jj;
  __syncthreads();

  for (int s=0;s<SLEN;++s){
    const float* grow = gi + ((size_t)s*BATCH + b)*H3;
    float g1 = 0.f, g2 = 0.f;
    if (jj < 512)  g1 = grow[jj];
    if (jj < HDIM) g2 = grow[2*HDIM + jj];
#define DL(i) uint4 p##i = Wp[(i)*H3];
    L20(DL)
#undef DL
    float ac0=0.f, ac1=0.f, ac2=0.f, ac3=0.f;
    #pragma unroll
    for (int k8=0;k8<12;++k8){
      uint4 w = Wlds[k8][jj];
      uint4 hq = *(const uint4*)&hpk[k8*4];
      ac0 = fdot2h(u2h(w.x),u2h(hq.x),ac0);
      ac1 = fdot2h(u2h(w.y),u2h(hq.y),ac1);
      ac2 = fdot2h(u2h(w.z),u2h(hq.z),ac2);
      ac3 = fdot2h(u2h(w.w),u2h(hq.w),ac3);
    }
#define DU(i) { uint4 hq = *(const uint4*)&hpk[(i)*4]; \
    ac0 = fdot2h(u2h(p##i.x),u2h(hq.x),ac0); \
    ac1 = fdot2h(u2h(p##i.y),u2h(hq.y),ac1); \
    ac2 = fdot2h(u2h(p##i.z),u2h(hq.z),ac2); \
    ac3 = fdot2h(u2h(p##i.w),u2h(hq.w),ac3); }
    L20(DU)
#undef DU
    float acc = (ac0+ac1)+(ac2+ac3) + bh;
    st[jj] = (jj < 512) ? (acc + g1) : acc;
    __syncthreads();
    if (jj < HDIM){
      float rr = fsig(st[jj]);
      float zz = fsig(st[HDIM + jj]);
      float nn = ftanh(g2 + rr*st[2*HDIM + jj]);
      float h2v = nn + zz*(hreg - nn);          // (1-z)*n + z*h
      hreg = h2v;
      int srow = dir ? (SLEN-1-s) : s;
      dst[(size_t)srow*BATCH*2*HDIM] = h2v;
      ((_Float16*)hpk)[jj] = (_Float16)h2v;
    }
    __syncthreads();
  }
}

// ---------- bridge: h0 = tanh([hf,hb] @ bridge_W.T + b) ----------
__global__ __launch_bounds__(256) void k_bridge(
    const float* __restrict__ enc_states,
    const float* __restrict__ bridge_W, const float* __restrict__ bridge_b,
    float* __restrict__ h_dec)
{
  int b = blockIdx.x, j = threadIdx.x;
  __shared__ float hcat[2*HDIM];
  hcat[j]        = enc_states[((size_t)(SLEN-1)*BATCH + b)*2*HDIM + j];          // forward final
  hcat[HDIM + j] = enc_states[(size_t)b*2*HDIM + HDIM + j];                      // backward final
  __syncthreads();
  const float* w = bridge_W + (size_t)j*2*HDIM;
  float4 a = {0.f,0.f,0.f,0.f};
  #pragma unroll 4
  for (int k=0;k<2*HDIM;k+=4){
    float4 h4 = *(const float4*)&hcat[k];
    float4 w4 = *(const float4*)&w[k];
    a.x=fmaf(h4.x,w4.x,a.x); a.y=fmaf(h4.y,w4.y,a.y);
    a.z=fmaf(h4.z,w4.z,a.z); a.w=fmaf(h4.w,w4.w,a.w);
  }
  h_dec[b*HDIM+j] = ftanh((a.x+a.y)+(a.z+a.w) + bridge_b[j]);
}

// ---------- fused decoder: all 15 steps in one kernel (block = batch row) ----------
__global__ __launch_bounds__(256) void k_dec(
    const float* __restrict__ proj,
    const float* __restrict__ enc_states,
    const float* __restrict__ attn_Wq,
    const float* __restrict__ attn_We,
    const float* __restrict__ dec_Wih,
    const float* __restrict__ dec_Whh,
    const float* __restrict__ dec_bhh,
    const float* __restrict__ gie_all,
    const float* __restrict__ h0,
    float* __restrict__ alphas_all,
    float* __restrict__ cat_all, _Float16* __restrict__ cat16)
{
  int b = blockIdx.x, j = threadIdx.x;
  __shared__ float h_s[HDIM], q_s[HDIM], we_s[HDIM], ctx_s[2*HDIM], sc[SLEN];
  __shared__ float red[8];
  h_s[j] = h0[b*HDIM + j];
  we_s[j] = attn_We[j];
  __syncthreads();

  for (int t=0;t<NDEC;++t){
    // q = h @ Wq.T
    {
      const float* wq = attn_Wq + (size_t)j*HDIM;
      float4 a = {0.f,0.f,0.f,0.f};
      #pragma unroll 8
      for (int k=0;k<HDIM;k+=4){
        float4 h4 = *(const float4*)&h_s[k];
        float4 w4 = *(const float4*)&wq[k];
        a.x=fmaf(h4.x,w4.x,a.x); a.y=fmaf(h4.y,w4.y,a.y);
        a.z=fmaf(h4.z,w4.z,a.z); a.w=fmaf(h4.w,w4.w,a.w);
      }
      q_s[j] = (a.x+a.y)+(a.z+a.w);
    }
    __syncthreads();
    // scores[s] = tanh(q + proj[s,b]) . We
    for (int s=j; s<SLEN; s+=256){
      const float* pr = proj + ((size_t)s*BATCH + b)*HDIM;
      float4 a = {0.f,0.f,0.f,0.f};
      #pragma unroll 4
      for (int k=0;k<HDIM;k+=4){
        float4 p4 = *(const float4*)&pr[k];
        float4 q4 = *(const float4*)&q_s[k];
        float4 w4 = *(const float4*)&we_s[k];
        a.x = fmaf(ftanh(q4.x+p4.x), w4.x, a.x);
        a.y = fmaf(ftanh(q4.y+p4.y), w4.y, a.y);
        a.z = fmaf(ftanh(q4.z+p4.z), w4.z, a.z);
        a.w = fmaf(ftanh(q4.w+p4.w), w4.w, a.w);
      }
      sc[s] = (a.x+a.y)+(a.z+a.w);
    }
    __syncthreads();
    // softmax over s
    float m = -1e30f;
    for (int s=j; s<SLEN; s+=256) m = fmaxf(m, sc[s]);
    m = block_max(m, red);
    float ssum = 0.f;
    for (int s=j; s<SLEN; s+=256){ float e = __expf(sc[s]-m); sc[s]=e; ssum+=e; }
    ssum = block_sum(ssum, red);
    float inv = 1.f/ssum;
    for (int s=j; s<SLEN; s+=256){
      float a = sc[s]*inv; sc[s]=a;
      alphas_all[((size_t)t*SLEN + s)*BATCH + b] = a;
    }
    __syncthreads();
    int r = t*BATCH + b;
    // context
    for (int d=j; d<2*HDIM; d+=256){
      const float* e0 = enc_states + (size_t)b*2*HDIM + d;
      float a0=0.f,a1=0.f,a2=0.f,a3=0.f;
      #pragma unroll 4
      for (int s=0;s<SLEN;s+=4){
        a0 = fmaf(sc[s+0], e0[(size_t)(s+0)*BATCH*2*HDIM], a0);
        a1 = fmaf(sc[s+1], e0[(size_t)(s+1)*BATCH*2*HDIM], a1);
        a2 = fmaf(sc[s+2], e0[(size_t)(s+2)*BATCH*2*HDIM], a2);
        a3 = fmaf(sc[s+3], e0[(size_t)(s+3)*BATCH*2*HDIM], a3);
      }
      float c = (a0+a1)+(a2+a3);
      ctx_s[d] = c;
      cat_all[(size_t)r*896 + 384 + d] = c;
      cat16[(size_t)r*896 + 384 + d] = (_Float16)c;
    }
    __syncthreads();
    // GRU cell
    float g[3], hh[3];
    #pragma unroll
    for (int gg=0; gg<3; ++gg){
      int jr = gg*HDIM + j;
      const float* wi = dec_Wih + (size_t)jr*640 + 128;
      float4 a = {0.f,0.f,0.f,0.f};
      #pragma unroll 4
      for (int k=0;k<2*HDIM;k+=4){
        float4 c4 = *(const float4*)&ctx_s[k];
        float4 w4 = *(const float4*)&wi[k];
        a.x=fmaf(c4.x,w4.x,a.x); a.y=fmaf(c4.y,w4.y,a.y);
        a.z=fmaf(c4.z,w4.z,a.z); a.w=fmaf(c4.w,w4.w,a.w);
      }
      g[gg] = gie_all[(size_t)r*H3 + jr] + (a.x+a.y)+(a.z+a.w);
      const float* wh = dec_Whh + (size_t)jr*HDIM;
      float4 h4a = {0.f,0.f,0.f,0.f};
      #pragma unroll 4
      for (int k=0;k<HDIM;k+=4){
        float4 h4 = *(const float4*)&h_s[k];
        float4 w4 = *(const float4*)&wh[k];
        h4a.x=fmaf(h4.x,w4.x,h4a.x); h4a.y=fmaf(h4.y,w4.y,h4a.y);
        h4a.z=fmaf(h4.z,w4.z,h4a.z); h4a.w=fmaf(h4.w,w4.w,h4a.w);
      }
      hh[gg] = dec_bhh[jr] + (h4a.x+h4a.y)+(h4a.z+h4a.w);
    }
    float rr = fsig(g[0]+hh[0]);
    float zz = fsig(g[1]+hh[1]);
    float nn = ftanh(g[2] + rr*hh[2]);
    float h2v = nn + zz*(h_s[j]-nn);
    __syncthreads();                       // all h_s reads done before overwrite
    h_s[j] = h2v;
    cat_all[(size_t)r*896 + 128 + j] = h2v;
    cat16[(size_t)r*896 + 128 + j] = (_Float16)h2v;
    __syncthreads();
  }
}

// ---------- p_gen = sigmoid(cat . pgen_W + b) ----------
__global__ __launch_bounds__(64) void k_pgen(
    const float* __restrict__ cat_all,
    const float* __restrict__ pgen_W, const float* __restrict__ pgen_b,
    float* __restrict__ pgen_all)
{
  int r = blockIdx.x;
  const float* c = cat_all + (size_t)r*896;
  float acc = 0.f;
  for (int k=threadIdx.x; k<896; k+=64) acc = fmaf(c[k], pgen_W[k], acc);
  acc = wred_sum(acc);
  if (threadIdx.x==0) pgen_all[r] = fsig(acc + pgen_b[0]);
}

// ---------- per-row softmax stats over V (f16 logits) ----------
__global__ __launch_bounds__(256) void k_rowred(
    const _Float16* __restrict__ logits,
    float* __restrict__ row_max, float* __restrict__ row_sum)
{
  int r = blockIdx.x;
  const uint4* row = (const uint4*)(logits + (size_t)r*VVOC);   // r*100000B: 16B-aligned
  __shared__ float red[8];
  float m = -1e30f;
  for (int v=threadIdx.x; v<VVOC/8; v+=256){
    uint4 x = row[v];
    h2 a=u2h(x.x), bb=u2h(x.y), c=u2h(x.z), d=u2h(x.w);
    float m1 = fmaxf(fmaxf((float)a.x,(float)a.y), fmaxf((float)bb.x,(float)bb.y));
    float m2 = fmaxf(fmaxf((float)c.x,(float)c.y), fmaxf((float)d.x,(float)d.y));
    m = fmaxf(m, fmaxf(m1,m2));
  }
  m = block_max(m, red);
  float s = 0.f;
  for (int v=threadIdx.x; v<VVOC/8; v+=256){
    uint4 x = row[v];
    h2 a=u2h(x.x), bb=u2h(x.y), c=u2h(x.z), d=u2h(x.w);
    s += __expf((float)a.x-m) + __expf((float)a.y-m) + __expf((float)bb.x-m) + __expf((float)bb.y-m)
       + __expf((float)c.x-m) + __expf((float)c.y-m) + __expf((float)d.x-m) + __expf((float)d.y-m);
  }
  s = block_sum(s, red);
  if (threadIdx.x==0){ row_max[r]=m; row_sum[r]=1.f/s; }
}

// ---------- write ext (linear domain); t=0 row = 0 ----------
__global__ __launch_bounds__(256) void k_final(
    const _Float16* __restrict__ logits, const float* __restrict__ pgen_all,
    const float* __restrict__ row_max, const float* __restrict__ row_sum,
    float* __restrict__ out)
{
  int v = blockIdx.x*256 + threadIdx.x;
  if (v >= VEXT) return;
  int b = blockIdx.y, t = blockIdx.z;
  size_t o = ((size_t)t*BATCH + b)*VEXT + v;
  if (t == 0){ out[o] = 0.f; return; }
  int r = (t-1)*BATCH + b;
  float val = 1e-12f;
  if (v < VVOC)
    val += pgen_all[r] * row_sum[r] * __expf((float)logits[(size_t)r*VVOC + v] - row_max[r]);
  out[o] = val;
}

// ---------- scatter copy-distribution ----------
__global__ __launch_bounds__(512) void k_scatter(
    const int* __restrict__ input_seq_ext,
    const float* __restrict__ alphas, const float* __restrict__ pgen_all,
    float* __restrict__ out)
{
  int r = blockIdx.x;               // t*32+b
  int s = threadIdx.x;
  if (s >= SLEN) return;
  int t = r >> 5, b = r & 31;
  float w = (1.f - pgen_all[r]) * alphas[((size_t)t*SLEN + s)*BATCH + b];
  int idx = input_seq_ext[b*SLEN + s];
  atomicAdd(&out[((size_t)(t+1)*BATCH + b)*VEXT + idx], w);
}

// ---------- log transform rows t>=1 ----------
__global__ __launch_bounds__(256) void k_log(float* __restrict__ out)
{
  int v = blockIdx.x*256 + threadIdx.x;
  if (v >= VEXT) return;
  int b = blockIdx.y, t = blockIdx.z + 1;
  size_t o = ((size_t)t*BATCH + b)*VEXT + v;
  out[o] = __logf(out[o]);
}

extern "C" void kernel_launch(void* const* d_in, const int* in_sizes, int n_in,
                              void* d_out, int out_size, void* d_ws, size_t ws_size,
                              hipStream_t stream)
{
  (void)in_sizes; (void)n_in; (void)out_size; (void)ws_size;
  const int*   input_seq     = (const int*)d_in[0];
  const int*   input_seq_ext = (const int*)d_in[1];
  const int*   target_seq    = (const int*)d_in[2];
  const float* embedding     = (const float*)d_in[3];
  const float* enc_Wih_f     = (const float*)d_in[4];
  const float* enc_Whh_f     = (const float*)d_in[5];
  const float* enc_bih_f     = (const float*)d_in[6];
  const float* enc_bhh_f     = (const float*)d_in[7];
  const float* enc_Wih_b     = (const float*)d_in[8];
  const float* enc_Whh_b     = (const float*)d_in[9];
  const float* enc_bih_b     = (const float*)d_in[10];
  const float* enc_bhh_b     = (const float*)d_in[11];
  const float* proj_W        = (const float*)d_in[12];
  const float* proj_b        = (const float*)d_in[13];
  const float* bridge_W      = (const float*)d_in[14];
  const float* bridge_b      = (const float*)d_in[15];
  const float* dec_Wih       = (const float*)d_in[16];
  const float* dec_Whh       = (const float*)d_in[17];
  const float* dec_bih       = (const float*)d_in[18];
  const float* dec_bhh       = (const float*)d_in[19];
  const float* attn_Wq       = (const float*)d_in[20];
  const float* attn_We       = (const float*)d_in[21];
  const float* lin_W         = (const float*)d_in[22];
  const float* lin_b         = (const float*)d_in[23];
  const float* pgen_W        = (const float*)d_in[24];
  const float* pgen_b        = (const float*)d_in[25];
  const float* out_W         = (const float*)d_in[26];
  const float* out_b         = (const float*)d_in[27];
  float* out = (float*)d_out;
  float* ws  = (float*)d_ws;

  // ---- workspace layout (float offsets). f16 buffers hold 2 halves per float slot.
  _Float16* emb16    = (_Float16*)(ws + 0);            // 12800x128 h   (409600 f)
  _Float16* Wih16_f  = (_Float16*)(ws + 409600);       // 768x128 h     (49152 f)
  _Float16* Wih16_b  = (_Float16*)(ws + 458752);       // 768x128 h     (49152 f)
  _Float16* proj_W16 = (_Float16*)(ws + 507904);       // 256x512 h     (65536 f)
  _Float16* lin_W16  = (_Float16*)(ws + 573440);       // 256x896 h     (114688 f)
  _Float16* cat16    = (_Float16*)(ws + 688128);       // 480x896 h     (215040 f)
  _Float16* lin16    = (_Float16*)(ws + 903168);       // 480x256 h     (61440 f)
  _Float16* dWih16   = (_Float16*)(ws + 964608);       // 768x640 h     (245760 f) -> ends 1210368
  float* enc_states  = ws + 1638400;                   // 400x32x512    (6553600)
  float* proj        = ws + 8192000;                   // 400x32x256    (3276800)
  float* gi_f        = ws + 11468800;                  // 12800x768     (9830400)  [dies after k_enc]
  float* gi_b        = ws + 21299200;                  //               (9830400)  [dies after k_enc]
  // post-k_enc reuse of the gi region:
  _Float16* logits16 = (_Float16*)(ws + 11468800);     // 480x50000 h   (12000000 f)
  _Float16* out_W16  = (_Float16*)(ws + 23468800);     // 50000x256 h   (6400000 f)
  _Float16* enc16    = (_Float16*)(ws + 29868800);     // 12800x512 h   (3276800 f) -> ends 33145600
  uint4* W16_f       = (uint4*)(ws + 35000000);        // k-major enc weights (98304 f)
  uint4* W16_b       = (uint4*)(ws + 35098304);        //               (98304 f) -> ends 35196608
  float* cat_all     = ws + 35468800;                  // 480x896       (430080)
  float* gie_all     = ws + 35898880;                  // 480x768       (368640)
  float* h_dec       = ws + 36267520;                  // 32x256        (8192)
  float* alphas      = ws + 36275712;                  // 15x400x32     (192000)
  float* pgen_all    = ws + 36467712;                  // 480
  float* row_max     = ws + 36468192;                  // 480
  float* row_sum     = ws + 36468672;                  // 480
  // total ~146 MB (same footprint as round 4)

  k_embed<<<dim3(SLEN*BATCH + NDEC*BATCH), dim3(64), 0, stream>>>(
      input_seq, target_seq, embedding, emb16, cat_all, cat16);

  // weight conversions (front; buffers outside gi region)
  k_cvtv<<<dim3((98304/8+255)/256), dim3(256), 0, stream>>>(enc_Wih_f, Wih16_f, 98304/8);
  k_cvtv<<<dim3((98304/8+255)/256), dim3(256), 0, stream>>>(enc_Wih_b, Wih16_b, 98304/8);
  k_cvtv<<<dim3((131072/8+255)/256), dim3(256), 0, stream>>>(proj_W, proj_W16, 131072/8);
  k_cvtv<<<dim3((229376/8+255)/256), dim3(256), 0, stream>>>(lin_W, lin_W16, 229376/8);
  k_cvtv<<<dim3((491520/8+255)/256), dim3(256), 0, stream>>>(dec_Wih, dWih16, 491520/8);
  k_cvt<<<dim3(H3), dim3(32), 0, stream>>>(enc_Whh_f, W16_f);
  k_cvt<<<dim3(H3), dim3(32), 0, stream>>>(enc_Whh_b, W16_b);

  // gi = emb @ Wih.T + bih (MFMA f16)
  k_gmm<<<dim3(6,100), dim3(256), 0, stream>>>(emb16, EDIM, Wih16_f, EDIM, enc_bih_f,
      gi_f, (_Float16*)nullptr, H3, SLEN*BATCH, H3, EDIM, 0);
  k_gmm<<<dim3(6,100), dim3(256), 0, stream>>>(emb16, EDIM, Wih16_b, EDIM, enc_bih_b,
      gi_b, (_Float16*)nullptr, H3, SLEN*BATCH, H3, EDIM, 1);

  k_enc<<<dim3(64), dim3(768), 0, stream>>>(gi_f, gi_b, W16_f, W16_b, enc_bhh_f, enc_bhh_b, enc_states);

  // post-enc conversions into the dead gi region
  k_cvtv<<<dim3((6553600/8+255)/256), dim3(256), 0, stream>>>(enc_states, enc16, 6553600/8);
  k_cvtv<<<dim3((12800000/8+255)/256), dim3(256), 0, stream>>>(out_W, out_W16, 12800000/8);

  // proj = enc_states @ proj_W.T + proj_b (MFMA)
  k_gmm<<<dim3(2,100), dim3(256), 0, stream>>>(enc16, 2*HDIM, proj_W16, 2*HDIM, proj_b,
      proj, (_Float16*)nullptr, HDIM, SLEN*BATCH, HDIM, 2*HDIM, 0);

  k_bridge<<<dim3(BATCH), dim3(256), 0, stream>>>(enc_states, bridge_W, bridge_b, h_dec);

  // decoder-embedding gate contributions (K=128 e-cols of cat), MFMA
  k_gmm<<<dim3(6,4), dim3(256), 0, stream>>>(cat16, 896, dWih16, 640, dec_bih,
      gie_all, (_Float16*)nullptr, H3, NDEC*BATCH, H3, EDIM, 0);

  // fused 15-step decoder
  k_dec<<<dim3(BATCH), dim3(256), 0, stream>>>(proj, enc_states, attn_Wq, attn_We,
      dec_Wih, dec_Whh, dec_bhh, gie_all, h_dec, alphas, cat_all, cat16);

  // epilogue: lin (f16 out), pgen, logits (f16 out), softmax stats, final, scatter, log
  k_gmm<<<dim3(2,4), dim3(256), 0, stream>>>(cat16, 896, lin_W16, 896, lin_b,
      (float*)nullptr, lin16, HDIM, NDEC*BATCH, HDIM, 896, 0);
  k_pgen<<<dim3(NDEC*BATCH), dim3(64), 0, stream>>>(cat_all, pgen_W, pgen_b, pgen_all);
  k_gmm<<<dim3(391,4), dim3(256), 0, stream>>>(lin16, HDIM, out_W16, HDIM, out_b,
      (float*)nullptr, logits16, VVOC, NDEC*BATCH, VVOC, HDIM, 0);
  k_rowred<<<dim3(NDEC*BATCH), dim3(256), 0, stream>>>(logits16, row_max, row_sum);
  k_final<<<dim3(196, BATCH, TLEN), dim3(256), 0, stream>>>(logits16, pgen_all, row_max, row_sum, out);
  k_scatter<<<dim3(NDEC*BATCH), dim3(512), 0, stream>>>(input_seq_ext, alphas, pgen_all, out);
  k_log<<<dim3(196, BATCH, NDEC), dim3(256), 0, stream>>>(out);
}

// Round 6
// 1197.743 us; speedup vs baseline: 5.6770x; 2.2337x over previous
//
#include <hip/hip_runtime.h>

#define SLEN 400
#define BATCH 32
#define TLEN 16
#define NDEC 15
#define EDIM 128
#define HDIM 256
#define H3 768
#define VVOC 50000
#define VEXT 50020
#define SCHUNK 50

// ---------- fast math helpers ----------
__device__ __forceinline__ float frcp(float x){ return __builtin_amdgcn_rcpf(x); }
__device__ __forceinline__ float fsig(float x){ return frcp(1.f + __expf(-x)); }
__device__ __forceinline__ float ftanh(float x){
  float e = __expf(2.f*x);
  return 1.f - 2.f*frcp(e + 1.f);
}

typedef _Float16 h2 __attribute__((ext_vector_type(2)));
typedef _Float16 half8 __attribute__((ext_vector_type(8)));
typedef float floatx4 __attribute__((ext_vector_type(4)));

__device__ __forceinline__ h2 u2h(unsigned u){ return __builtin_bit_cast(h2, u); }
__device__ __forceinline__ unsigned pkh(float a, float b){
  h2 v; v.x=(_Float16)a; v.y=(_Float16)b;
  return __builtin_bit_cast(unsigned, v);
}

#if __has_builtin(__builtin_amdgcn_fdot2)
__device__ __forceinline__ float fdot2h(h2 a, h2 b, float c){
  return __builtin_amdgcn_fdot2(a, b, c, false);
}
#else
__device__ __forceinline__ float fdot2h(h2 a, h2 b, float c){
  return fmaf((float)a.x,(float)b.x, fmaf((float)a.y,(float)b.y, c));
}
#endif

__device__ __forceinline__ float wred_sum(float v){
  #pragma unroll
  for (int o=32;o>0;o>>=1) v += __shfl_down(v,o,64);
  return v;
}
__device__ __forceinline__ float wred_max(float v){
  #pragma unroll
  for (int o=32;o>0;o>>=1) v = fmaxf(v, __shfl_down(v,o,64));
  return v;
}
__device__ __forceinline__ float block_max(float v, float* red){
  v = wred_max(v);
  int lane = threadIdx.x & 63, wid = threadIdx.x >> 6;
  if (!lane) red[wid] = v;
  __syncthreads();
  if (threadIdx.x == 0){
    float m = red[0];
    int nw = blockDim.x >> 6;
    for (int w=1;w<nw;++w) m = fmaxf(m, red[w]);
    red[0] = m;
  }
  __syncthreads();
  v = red[0];
  __syncthreads();
  return v;
}
__device__ __forceinline__ float block_sum(float v, float* red){
  v = wred_sum(v);
  int lane = threadIdx.x & 63, wid = threadIdx.x >> 6;
  if (!lane) red[wid] = v;
  __syncthreads();
  if (threadIdx.x == 0){
    float m = red[0];
    int nw = blockDim.x >> 6;
    for (int w=1;w<nw;++w) m += red[w];
    red[0] = m;
  }
  __syncthreads();
  v = red[0];
  __syncthreads();
  return v;
}

// ---------- embedding gather ----------
__global__ __launch_bounds__(64) void k_embed(
    const int* __restrict__ input_seq, const int* __restrict__ target_seq,
    const float* __restrict__ embedding,
    _Float16* __restrict__ emb16, float* __restrict__ cat_all, _Float16* __restrict__ cat16)
{
  int row = blockIdx.x;
  if (row < SLEN*BATCH) {
    int s = row >> 5, b = row & 31;
    int tok = input_seq[b*SLEN + s];
    float2 v = ((const float2*)(embedding + (size_t)tok*EDIM))[threadIdx.x];
    ((unsigned*)(emb16 + (size_t)row*EDIM))[threadIdx.x] = pkh(v.x, v.y);
  } else {
    int rr = row - SLEN*BATCH;
    int t = rr >> 5, b = rr & 31;
    int tok = target_seq[b*TLEN + t];       // toks = target_seq[:, :T-1].T
    float2 v = ((const float2*)(embedding + (size_t)tok*EDIM))[threadIdx.x];
    ((float2*)(cat_all + (size_t)rr*896))[threadIdx.x] = v;       // cat cols [0:128) = e
    ((unsigned*)(cat16 + (size_t)rr*896))[threadIdx.x] = pkh(v.x, v.y);
  }
}

// ---------- flat fp32 -> f16 convert (8 elems/thread) ----------
__global__ __launch_bounds__(256) void k_cvtv(
    const float* __restrict__ S, _Float16* __restrict__ D, int n8)
{
  int i = blockIdx.x*256 + threadIdx.x;
  if (i >= n8) return;
  float4 a = ((const float4*)S)[i*2];
  float4 b = ((const float4*)S)[i*2+1];
  uint4 o;
  o.x = pkh(a.x,a.y); o.y = pkh(a.z,a.w);
  o.z = pkh(b.x,b.y); o.w = pkh(b.z,b.w);
  ((uint4*)D)[i] = o;
}

// ---------- generic k-major f16 packer: D[k8][row] = 8 halves of W[row, coloff+k8*8..] ----------
// grid = nrows, threads = K/8
__global__ void k_cvtk(
    const float* __restrict__ W, uint4* __restrict__ D, int ldw, int coloff)
{
  int row = blockIdx.x, k8 = threadIdx.x, nrows = gridDim.x;
  const float* s = W + (size_t)row*ldw + coloff + k8*8;
  float4 x = *(const float4*)s;
  float4 y = *(const float4*)(s+4);
  uint4 o;
  o.x = pkh(x.x,x.y); o.y = pkh(x.z,x.w);
  o.z = pkh(y.x,y.y); o.w = pkh(y.z,y.w);
  D[(size_t)k8*nrows + row] = o;
}

// ---------- MFMA f16 GEMM: C[m,n] = sum_k A16[am,k]*W16[n,k] + bias[n] ----------
__global__ __launch_bounds__(256) void k_gmm(
    const _Float16* __restrict__ A, int lda,
    const _Float16* __restrict__ W, int ldw,
    const float* __restrict__ bias,
    float* __restrict__ C, _Float16* __restrict__ C16, int ldc,
    int M, int N, int K, int rev)
{
  __shared__ __align__(16) _Float16 Al[128*64];
  __shared__ __align__(16) _Float16 Wl[128*64];
  int tid = threadIdx.x;
  int wv = tid >> 6, l = tid & 63;
  int wr = (wv>>1)*64, wc = (wv&1)*64;
  int lr = l & 15, lh = l >> 4;
  int m0 = blockIdx.y*128, n0 = blockIdx.x*128;
  floatx4 acc[4][4];
  #pragma unroll
  for (int i=0;i<4;++i)
    #pragma unroll
    for (int jn=0;jn<4;++jn) acc[i][jn] = (floatx4){0.f,0.f,0.f,0.f};

  for (int kc=0; kc<K; kc+=64){
    #pragma unroll
    for (int i=0;i<4;++i){
      int idx = tid + i*256;
      int row = idx>>3, c = idx&7;
      int m = m0+row;
      uint4 v = {0u,0u,0u,0u};
      if (m < M){
        int am = m;
        if (rev){ int s = m>>5; am = ((SLEN-1-s)<<5)|(m&31); }
        v = *(const uint4*)&A[(size_t)am*lda + kc + c*8];
      }
      *(uint4*)&Al[row*64 + ((c ^ (row&7))<<3)] = v;
    }
    #pragma unroll
    for (int i=0;i<4;++i){
      int idx = tid + i*256;
      int row = idx>>3, c = idx&7;
      int n = n0+row;
      uint4 v = {0u,0u,0u,0u};
      if (n < N) v = *(const uint4*)&W[(size_t)n*ldw + kc + c*8];
      *(uint4*)&Wl[row*64 + ((c ^ (row&7))<<3)] = v;
    }
    __syncthreads();
    #pragma unroll
    for (int ks=0; ks<2; ++ks){
      half8 af0, af1, af2, af3, bf0, bf1, bf2, bf3;
      {
        int c = ks*4 + lh;
        int r0 = wr + 0*16 + lr, r1 = wr + 1*16 + lr, r2 = wr + 2*16 + lr, r3 = wr + 3*16 + lr;
        af0 = *(const half8*)&Al[r0*64 + ((c ^ (r0&7))<<3)];
        af1 = *(const half8*)&Al[r1*64 + ((c ^ (r1&7))<<3)];
        af2 = *(const half8*)&Al[r2*64 + ((c ^ (r2&7))<<3)];
        af3 = *(const half8*)&Al[r3*64 + ((c ^ (r3&7))<<3)];
        int n0l = wc + 0*16 + lr, n1l = wc + 1*16 + lr, n2l = wc + 2*16 + lr, n3l = wc + 3*16 + lr;
        bf0 = *(const half8*)&Wl[n0l*64 + ((c ^ (n0l&7))<<3)];
        bf1 = *(const half8*)&Wl[n1l*64 + ((c ^ (n1l&7))<<3)];
        bf2 = *(const half8*)&Wl[n2l*64 + ((c ^ (n2l&7))<<3)];
        bf3 = *(const half8*)&Wl[n3l*64 + ((c ^ (n3l&7))<<3)];
      }
      half8 afs[4] = {af0, af1, af2, af3};
      half8 bfs[4] = {bf0, bf1, bf2, bf3};
      #pragma unroll
      for (int mi=0;mi<4;++mi)
        #pragma unroll
        for (int ni=0;ni<4;++ni)
          acc[mi][ni] = __builtin_amdgcn_mfma_f32_16x16x32_f16(afs[mi], bfs[ni], acc[mi][ni], 0,0,0);
    }
    __syncthreads();
  }
  #pragma unroll
  for (int mi=0;mi<4;++mi){
    #pragma unroll
    for (int q=0;q<4;++q){
      int m = m0 + wr + mi*16 + lh*4 + q;
      if (m < M){
        #pragma unroll
        for (int ni=0;ni<4;++ni){
          int n = n0 + wc + ni*16 + lr;
          if (n < N){
            float v = acc[mi][ni][q] + bias[n];
            if (C)   C[(size_t)m*ldc + n] = v;
            if (C16) C16[(size_t)m*ldc + n] = (_Float16)v;
          }
        }
      }
    }
  }
}

// ---------- encoder GRU recurrence (unchanged round-4 structure) ----------
#define L20(M) M(12) M(13) M(14) M(15) M(16) M(17) M(18) M(19) M(20) M(21) \
               M(22) M(23) M(24) M(25) M(26) M(27) M(28) M(29) M(30) M(31)

__global__ __launch_bounds__(768) void k_enc(
    const float* __restrict__ gi_f, const float* __restrict__ gi_b,
    const uint4* __restrict__ W16_f, const uint4* __restrict__ W16_b,
    const float* __restrict__ bhh_f, const float* __restrict__ bhh_b,
    float* __restrict__ enc_states)
{
  int dir = blockIdx.x >> 5, b = blockIdx.x & 31;
  int jj = threadIdx.x;
  const float* gi  = dir ? gi_b  : gi_f;
  const uint4* Wp  = (dir ? W16_b : W16_f) + jj;
  float bh = (dir ? bhh_b : bhh_f)[jj];

  __shared__ __align__(16) unsigned hpk[HDIM/2];
  __shared__ __align__(16) float st[H3];
  __shared__ uint4 Wlds[12][H3];

  #pragma unroll
  for (int k8=0;k8<12;++k8) Wlds[k8][jj] = Wp[k8*H3];

  if (jj < HDIM/2) hpk[jj] = 0u;
  float hreg = 0.f;
  float* dst = enc_states + (size_t)b*2*HDIM + dir*HDIM + jj;
  __syncthreads();

  for (int s=0;s<SLEN;++s){
    const float* grow = gi + ((size_t)s*BATCH + b)*H3;
    float g1 = 0.f, g2 = 0.f;
    if (jj < 512)  g1 = grow[jj];
    if (jj < HDIM) g2 = grow[2*HDIM + jj];
#define DL(i) uint4 p##i = Wp[(i)*H3];
    L20(DL)
#undef DL
    float ac0=0.f, ac1=0.f, ac2=0.f, ac3=0.f;
    #pragma unroll
    for (int k8=0;k8<12;++k8){
      uint4 w = Wlds[k8][jj];
      uint4 hq = *(const uint4*)&hpk[k8*4];
      ac0 = fdot2h(u2h(w.x),u2h(hq.x),ac0);
      ac1 = fdot2h(u2h(w.y),u2h(hq.y),ac1);
      ac2 = fdot2h(u2h(w.z),u2h(hq.z),ac2);
      ac3 = fdot2h(u2h(w.w),u2h(hq.w),ac3);
    }
#define DU(i) { uint4 hq = *(const uint4*)&hpk[(i)*4]; \
    ac0 = fdot2h(u2h(p##i.x),u2h(hq.x),ac0); \
    ac1 = fdot2h(u2h(p##i.y),u2h(hq.y),ac1); \
    ac2 = fdot2h(u2h(p##i.z),u2h(hq.z),ac2); \
    ac3 = fdot2h(u2h(p##i.w),u2h(hq.w),ac3); }
    L20(DU)
#undef DU
    float acc = (ac0+ac1)+(ac2+ac3) + bh;
    st[jj] = (jj < 512) ? (acc + g1) : acc;
    __syncthreads();
    if (jj < HDIM){
      float rr = fsig(st[jj]);
      float zz = fsig(st[HDIM + jj]);
      float nn = ftanh(g2 + rr*st[2*HDIM + jj]);
      float h2v = nn + zz*(hreg - nn);
      hreg = h2v;
      int srow = dir ? (SLEN-1-s) : s;
      dst[(size_t)srow*BATCH*2*HDIM] = h2v;
      ((_Float16*)hpk)[jj] = (_Float16)h2v;
    }
    __syncthreads();
  }
}

// ---------- bridge: h0 = tanh([hf,hb] @ bridge_W.T + b) ----------
__global__ __launch_bounds__(256) void k_bridge(
    const float* __restrict__ enc_states,
    const float* __restrict__ bridge_W, const float* __restrict__ bridge_b,
    float* __restrict__ h_out)
{
  int b = blockIdx.x, j = threadIdx.x;
  __shared__ float hcat[2*HDIM];
  hcat[j]        = enc_states[((size_t)(SLEN-1)*BATCH + b)*2*HDIM + j];
  hcat[HDIM + j] = enc_states[(size_t)b*2*HDIM + HDIM + j];
  __syncthreads();
  const float* w = bridge_W + (size_t)j*2*HDIM;
  float4 a = {0.f,0.f,0.f,0.f};
  #pragma unroll 4
  for (int k=0;k<2*HDIM;k+=4){
    float4 h4 = *(const float4*)&hcat[k];
    float4 w4 = *(const float4*)&w[k];
    a.x=fmaf(h4.x,w4.x,a.x); a.y=fmaf(h4.y,w4.y,a.y);
    a.z=fmaf(h4.z,w4.z,a.z); a.w=fmaf(h4.w,w4.w,a.w);
  }
  h_out[b*HDIM+j] = ftanh((a.x+a.y)+(a.z+a.w) + bridge_b[j]);
}

// ---------- decoder step part B: q + attention scores + e + partial sums/ctx ----------
// grid (8 s-chunks, 32 b) x 256 thr. No max-subtraction: |score| <= ||We||_1 (~4), exp safe.
__global__ __launch_bounds__(256) void k_attnB(
    int t,
    const _Float16* __restrict__ proj16,
    const _Float16* __restrict__ enc16,
    const uint4* __restrict__ Wq16k,
    const float* __restrict__ attn_We,
    const float* __restrict__ hin,
    float* __restrict__ alphas_e,
    float* __restrict__ sum_part,
    float* __restrict__ ctx_part)
{
  int ch = blockIdx.x, b = blockIdx.y;
  int tid = threadIdx.x;
  __shared__ float q_s[HDIM], we_s[HDIM], sc[SCHUNK], red[8];
  __shared__ __align__(16) unsigned hq[HDIM/2];

  we_s[tid] = attn_We[tid];
  if (tid < HDIM/2){
    float2 hv = *(const float2*)&hin[b*HDIM + tid*2];
    hq[tid] = pkh(hv.x, hv.y);
  }
  __syncthreads();
  // q[i] = sum_k Wq[i,k] h[k]
  {
    float a0=0.f,a1=0.f,a2=0.f,a3=0.f;
    #pragma unroll
    for (int k8=0;k8<32;++k8){
      uint4 w = Wq16k[(size_t)k8*HDIM + tid];
      uint4 hp = *(const uint4*)&hq[k8*4];
      a0 = fdot2h(u2h(w.x),u2h(hp.x),a0);
      a1 = fdot2h(u2h(w.y),u2h(hp.y),a1);
      a2 = fdot2h(u2h(w.z),u2h(hp.z),a2);
      a3 = fdot2h(u2h(w.w),u2h(hp.w),a3);
    }
    q_s[tid] = (a0+a1)+(a2+a3);
  }
  __syncthreads();
  // scores: wave w handles s-rows ch*50 + {w, w+4, ...}
  {
    int wave = tid >> 6, lane = tid & 63;
    int d0 = lane*4;
    float4 qv = *(const float4*)&q_s[d0];
    float4 wv = *(const float4*)&we_s[d0];
    for (int is = wave; is < SCHUNK; is += 4){
      int s = ch*SCHUNK + is;
      uint2 p = *(const uint2*)&proj16[((size_t)(s*BATCH + b))*HDIM + d0];
      h2 pa = u2h(p.x), pb = u2h(p.y);
      float v = ftanh(qv.x+(float)pa.x)*wv.x + ftanh(qv.y+(float)pa.y)*wv.y
              + ftanh(qv.z+(float)pb.x)*wv.z + ftanh(qv.w+(float)pb.y)*wv.w;
      v = wred_sum(v);
      if (lane == 0){
        float e = __expf(v);
        sc[is] = e;
        alphas_e[((size_t)t*SLEN + s)*BATCH + b] = e;
      }
    }
  }
  __syncthreads();
  // partial sum of e
  {
    float sv = (tid < SCHUNK) ? sc[tid] : 0.f;
    sv = block_sum(sv, red);
    if (tid == 0) sum_part[b*8 + ch] = sv;
  }
  // partial ctx: thread owns d = 2t, 2t+1
  {
    float a0=0.f, a1=0.f;
    for (int is=0; is<SCHUNK; ++is){
      int s = ch*SCHUNK + is;
      unsigned u = *(const unsigned*)&enc16[((size_t)(s*BATCH + b) << 9) + tid*2];
      h2 ev = u2h(u);
      float e = sc[is];
      a0 = fmaf(e, (float)ev.x, a0);
      a1 = fmaf(e, (float)ev.y, a1);
    }
    float2 o; o.x = a0; o.y = a1;
    *(float2*)&ctx_part[(((size_t)b*8 + ch) << 9) + tid*2] = o;
  }
}

// ---------- decoder step part D: ctx reduce + GRU + h/cat writes ----------
// grid (8 j-chunks, 32 b) x 256 thr; thread = (slice 0..7, j_local 0..31).
__global__ __launch_bounds__(256) void k_gruD(
    int t,
    const float* __restrict__ ctx_part,
    const float* __restrict__ sum_part,
    const float* __restrict__ gie_all,
    const uint4* __restrict__ dWck16,
    const uint4* __restrict__ dWhk16,
    const float* __restrict__ dec_bhh,
    const float* __restrict__ hin,
    float* __restrict__ hout,
    float* __restrict__ cat_all, _Float16* __restrict__ cat16,
    float* __restrict__ sums_all)
{
  int ch = blockIdx.x, b = blockIdx.y;
  int tid = threadIdx.x;
  int jl = tid & 31, slice = tid >> 5;
  __shared__ __align__(16) unsigned cpk[HDIM], hpk[HDIM/2];
  __shared__ float hf[HDIM];
  __shared__ float pc[3][8][32], ph[3][8][32];
  __shared__ float invs;

  if (tid == 0){
    float ssum = 0.f;
    #pragma unroll
    for (int c=0;c<8;++c) ssum += sum_part[b*8 + c];
    float inv = 1.f/ssum;
    invs = inv;
    if (ch == 0) sums_all[t*BATCH + b] = inv;
  }
  if (tid < HDIM/2){
    float2 hv = *(const float2*)&hin[b*HDIM + tid*2];
    hpk[tid] = pkh(hv.x, hv.y);
    hf[tid*2] = hv.x; hf[tid*2+1] = hv.y;
  }
  __syncthreads();
  // ctx reduce + normalize; pack f16; chunk0 writes cat
  {
    int d0 = tid*2;
    float c0=0.f, c1=0.f;
    #pragma unroll
    for (int c=0;c<8;++c){
      float2 v = *(const float2*)&ctx_part[(((size_t)b*8 + c) << 9) + d0];
      c0 += v.x; c1 += v.y;
    }
    c0 *= invs; c1 *= invs;
    cpk[tid] = pkh(c0, c1);
    if (ch == 0){
      int r = t*BATCH + b;
      cat_all[(size_t)r*896 + 384 + d0]     = c0;
      cat_all[(size_t)r*896 + 384 + d0 + 1] = c1;
      cat16[(size_t)r*896 + 384 + d0]     = (_Float16)c0;
      cat16[(size_t)r*896 + 384 + d0 + 1] = (_Float16)c1;
    }
  }
  __syncthreads();
  // gate dots: 3 gates, ctx(K=512) + h(K=256), k-slice per thread
  {
    int jb = ch*32 + jl;
    float c0=0.f,c1=0.f,c2=0.f, g0=0.f,g1=0.f,g2=0.f;
    #pragma unroll
    for (int i=0;i<8;++i){
      int k8 = slice*8 + i;
      uint4 hq = *(const uint4*)&cpk[k8*4];
      uint4 w0 = dWck16[(size_t)k8*H3 + jb];
      uint4 w1 = dWck16[(size_t)k8*H3 + 256 + jb];
      uint4 w2 = dWck16[(size_t)k8*H3 + 512 + jb];
      c0 = fdot2h(u2h(w0.x),u2h(hq.x),c0); c0 = fdot2h(u2h(w0.y),u2h(hq.y),c0);
      c0 = fdot2h(u2h(w0.z),u2h(hq.z),c0); c0 = fdot2h(u2h(w0.w),u2h(hq.w),c0);
      c1 = fdot2h(u2h(w1.x),u2h(hq.x),c1); c1 = fdot2h(u2h(w1.y),u2h(hq.y),c1);
      c1 = fdot2h(u2h(w1.z),u2h(hq.z),c1); c1 = fdot2h(u2h(w1.w),u2h(hq.w),c1);
      c2 = fdot2h(u2h(w2.x),u2h(hq.x),c2); c2 = fdot2h(u2h(w2.y),u2h(hq.y),c2);
      c2 = fdot2h(u2h(w2.z),u2h(hq.z),c2); c2 = fdot2h(u2h(w2.w),u2h(hq.w),c2);
    }
    #pragma unroll
    for (int i=0;i<4;++i){
      int k8 = slice*4 + i;
      uint4 hq = *(const uint4*)&hpk[k8*4];
      uint4 w0 = dWhk16[(size_t)k8*H3 + jb];
      uint4 w1 = dWhk16[(size_t)k8*H3 + 256 + jb];
      uint4 w2 = dWhk16[(size_t)k8*H3 + 512 + jb];
      g0 = fdot2h(u2h(w0.x),u2h(hq.x),g0); g0 = fdot2h(u2h(w0.y),u2h(hq.y),g0);
      g0 = fdot2h(u2h(w0.z),u2h(hq.z),g0); g0 = fdot2h(u2h(w0.w),u2h(hq.w),g0);
      g1 = fdot2h(u2h(w1.x),u2h(hq.x),g1); g1 = fdot2h(u2h(w1.y),u2h(hq.y),g1);
      g1 = fdot2h(u2h(w1.z),u2h(hq.z),g1); g1 = fdot2h(u2h(w1.w),u2h(hq.w),g1);
      g2 = fdot2h(u2h(w2.x),u2h(hq.x),g2); g2 = fdot2h(u2h(w2.y),u2h(hq.y),g2);
      g2 = fdot2h(u2h(w2.z),u2h(hq.z),g2); g2 = fdot2h(u2h(w2.w),u2h(hq.w),g2);
    }
    pc[0][slice][jl]=c0; pc[1][slice][jl]=c1; pc[2][slice][jl]=c2;
    ph[0][slice][jl]=g0; ph[1][slice][jl]=g1; ph[2][slice][jl]=g2;
  }
  __syncthreads();
  if (tid < 32){
    int j = tid, r = t*BATCH + b;
    int jj = ch*32 + j;
    float gi0 = gie_all[(size_t)r*H3 + jj];
    float gi1 = gie_all[(size_t)r*H3 + 256 + jj];
    float gi2 = gie_all[(size_t)r*H3 + 512 + jj];
    float gh0 = dec_bhh[jj], gh1 = dec_bhh[256 + jj], gh2 = dec_bhh[512 + jj];
    #pragma unroll
    for (int c=0;c<8;++c){
      gi0 += pc[0][c][j]; gi1 += pc[1][c][j]; gi2 += pc[2][c][j];
      gh0 += ph[0][c][j]; gh1 += ph[1][c][j]; gh2 += ph[2][c][j];
    }
    float rr = fsig(gi0 + gh0);
    float zz = fsig(gi1 + gh1);
    float nn = ftanh(gi2 + rr*gh2);
    float hp = hf[jj];
    float h2v = nn + zz*(hp - nn);
    hout[b*HDIM + jj] = h2v;
    cat_all[(size_t)r*896 + 128 + jj] = h2v;
    cat16[(size_t)r*896 + 128 + jj] = (_Float16)h2v;
  }
}

// ---------- p_gen = sigmoid(cat . pgen_W + b) ----------
__global__ __launch_bounds__(64) void k_pgen(
    const float* __restrict__ cat_all,
    const float* __restrict__ pgen_W, const float* __restrict__ pgen_b,
    float* __restrict__ pgen_all)
{
  int r = blockIdx.x;
  const float* c = cat_all + (size_t)r*896;
  float acc = 0.f;
  for (int k=threadIdx.x; k<896; k+=64) acc = fmaf(c[k], pgen_W[k], acc);
  acc = wred_sum(acc);
  if (threadIdx.x==0) pgen_all[r] = fsig(acc + pgen_b[0]);
}

// ---------- per-row softmax stats over V (f16 logits) ----------
__global__ __launch_bounds__(256) void k_rowred(
    const _Float16* __restrict__ logits,
    float* __restrict__ row_max, float* __restrict__ row_sum)
{
  int r = blockIdx.x;
  const uint4* row = (const uint4*)(logits + (size_t)r*VVOC);
  __shared__ float red[8];
  float m = -1e30f;
  for (int v=threadIdx.x; v<VVOC/8; v+=256){
    uint4 x = row[v];
    h2 a=u2h(x.x), bb=u2h(x.y), c=u2h(x.z), d=u2h(x.w);
    float m1 = fmaxf(fmaxf((float)a.x,(float)a.y), fmaxf((float)bb.x,(float)bb.y));
    float m2 = fmaxf(fmaxf((float)c.x,(float)c.y), fmaxf((float)d.x,(float)d.y));
    m = fmaxf(m, fmaxf(m1,m2));
  }
  m = block_max(m, red);
  float s = 0.f;
  for (int v=threadIdx.x; v<VVOC/8; v+=256){
    uint4 x = row[v];
    h2 a=u2h(x.x), bb=u2h(x.y), c=u2h(x.z), d=u2h(x.w);
    s += __expf((float)a.x-m) + __expf((float)a.y-m) + __expf((float)bb.x-m) + __expf((float)bb.y-m)
       + __expf((float)c.x-m) + __expf((float)c.y-m) + __expf((float)d.x-m) + __expf((float)d.y-m);
  }
  s = block_sum(s, red);
  if (threadIdx.x==0){ row_max[r]=m; row_sum[r]=1.f/s; }
}

// ---------- write ext (linear domain); t=0 row = 0 ----------
__global__ __launch_bounds__(256) void k_final(
    const _Float16* __restrict__ logits, const float* __restrict__ pgen_all,
    const float* __restrict__ row_max, const float* __restrict__ row_sum,
    float* __restrict__ out)
{
  int v = blockIdx.x*256 + threadIdx.x;
  if (v >= VEXT) return;
  int b = blockIdx.y, t = blockIdx.z;
  size_t o = ((size_t)t*BATCH + b)*VEXT + v;
  if (t == 0){ out[o] = 0.f; return; }
  int r = (t-1)*BATCH + b;
  float val = 1e-12f;
  if (v < VVOC)
    val += pgen_all[r] * row_sum[r] * __expf((float)logits[(size_t)r*VVOC + v] - row_max[r]);
  out[o] = val;
}

// ---------- scatter copy-distribution (alphas = e * inv_sum) ----------
__global__ __launch_bounds__(512) void k_scatter(
    const int* __restrict__ input_seq_ext,
    const float* __restrict__ alphas_e, const float* __restrict__ sums_all,
    const float* __restrict__ pgen_all,
    float* __restrict__ out)
{
  int r = blockIdx.x;               // t*32+b
  int s = threadIdx.x;
  if (s >= SLEN) return;
  int t = r >> 5, b = r & 31;
  float w = (1.f - pgen_all[r]) * alphas_e[((size_t)t*SLEN + s)*BATCH + b] * sums_all[r];
  int idx = input_seq_ext[b*SLEN + s];
  atomicAdd(&out[((size_t)(t+1)*BATCH + b)*VEXT + idx], w);
}

// ---------- log transform rows t>=1 ----------
__global__ __launch_bounds__(256) void k_log(float* __restrict__ out)
{
  int v = blockIdx.x*256 + threadIdx.x;
  if (v >= VEXT) return;
  int b = blockIdx.y, t = blockIdx.z + 1;
  size_t o = ((size_t)t*BATCH + b)*VEXT + v;
  out[o] = __logf(out[o]);
}

extern "C" void kernel_launch(void* const* d_in, const int* in_sizes, int n_in,
                              void* d_out, int out_size, void* d_ws, size_t ws_size,
                              hipStream_t stream)
{
  (void)in_sizes; (void)n_in; (void)out_size; (void)ws_size;
  const int*   input_seq     = (const int*)d_in[0];
  const int*   input_seq_ext = (const int*)d_in[1];
  const int*   target_seq    = (const int*)d_in[2];
  const float* embedding     = (const float*)d_in[3];
  const float* enc_Wih_f     = (const float*)d_in[4];
  const float* enc_Whh_f     = (const float*)d_in[5];
  const float* enc_bih_f     = (const float*)d_in[6];
  const float* enc_bhh_f     = (const float*)d_in[7];
  const float* enc_Wih_b     = (const float*)d_in[8];
  const float* enc_Whh_b     = (const float*)d_in[9];
  const float* enc_bih_b     = (const float*)d_in[10];
  const float* enc_bhh_b     = (const float*)d_in[11];
  const float* proj_W        = (const float*)d_in[12];
  const float* proj_b        = (const float*)d_in[13];
  const float* bridge_W      = (const float*)d_in[14];
  const float* bridge_b      = (const float*)d_in[15];
  const float* dec_Wih       = (const float*)d_in[16];
  const float* dec_Whh       = (const float*)d_in[17];
  const float* dec_bih       = (const float*)d_in[18];
  const float* dec_bhh       = (const float*)d_in[19];
  const float* attn_Wq       = (const float*)d_in[20];
  const float* attn_We       = (const float*)d_in[21];
  const float* lin_W         = (const float*)d_in[22];
  const float* lin_b         = (const float*)d_in[23];
  const float* pgen_W        = (const float*)d_in[24];
  const float* pgen_b        = (const float*)d_in[25];
  const float* out_W         = (const float*)d_in[26];
  const float* out_b         = (const float*)d_in[27];
  float* out = (float*)d_out;
  float* ws  = (float*)d_ws;

  // ---- workspace layout (float offsets); same 146 MB footprint as round 5.
  _Float16* emb16    = (_Float16*)(ws + 0);            // 409600 f
  _Float16* Wih16_f  = (_Float16*)(ws + 409600);       // 49152 f
  _Float16* Wih16_b  = (_Float16*)(ws + 458752);       // 49152 f
  _Float16* proj_W16 = (_Float16*)(ws + 507904);       // 65536 f
  _Float16* lin_W16  = (_Float16*)(ws + 573440);       // 114688 f
  _Float16* cat16    = (_Float16*)(ws + 688128);       // 215040 f
  _Float16* lin16    = (_Float16*)(ws + 903168);       // 61440 f
  _Float16* dWih16   = (_Float16*)(ws + 964608);       // 245760 f -> 1210368
  float* enc_states  = ws + 1638400;                   // 6553600
  _Float16* proj16   = (_Float16*)(ws + 8192000);      // 1638400 f (f16 proj)
  float* gi_f        = ws + 11468800;                  // 9830400 [dies after k_enc]
  float* gi_b        = ws + 21299200;                  // 9830400 [dies after k_enc]
  _Float16* logits16 = (_Float16*)(ws + 11468800);     // 12000000 f
  _Float16* out_W16  = (_Float16*)(ws + 23468800);     // 6400000 f
  _Float16* enc16    = (_Float16*)(ws + 29868800);     // 3276800 f -> 33145600
  // region [33145600, 35000000): decoder-step buffers (outside gi live range)
  uint4* Wq16k       = (uint4*)(ws + 33145600);        // 32768 f
  uint4* dWck16      = (uint4*)(ws + 33178368);        // 196608 f
  uint4* dWhk16      = (uint4*)(ws + 33374976);        // 98304 f
  float* ctx_part    = ws + 33473280;                  // 131072 f
  float* sum_part    = ws + 33604352;                  // 256 f
  float* sums_all    = ws + 33604608;                  // 480 f
  float* hbuf0       = ws + 33605088;                  // 8192 f
  float* hbuf1       = ws + 33613280;                  // 8192 f -> 33621472
  uint4* W16_f       = (uint4*)(ws + 35000000);        // 98304 f
  uint4* W16_b       = (uint4*)(ws + 35098304);        // 98304 f
  float* cat_all     = ws + 35468800;                  // 430080
  float* gie_all     = ws + 35898880;                  // 368640
  float* alphas_e    = ws + 36275712;                  // 192000 (un-normalized e)
  float* pgen_all    = ws + 36467712;                  // 480
  float* row_max     = ws + 36468192;                  // 480
  float* row_sum     = ws + 36468672;                  // 480

  k_embed<<<dim3(SLEN*BATCH + NDEC*BATCH), dim3(64), 0, stream>>>(
      input_seq, target_seq, embedding, emb16, cat_all, cat16);

  // weight conversions
  k_cvtv<<<dim3((98304/8+255)/256), dim3(256), 0, stream>>>(enc_Wih_f, Wih16_f, 98304/8);
  k_cvtv<<<dim3((98304/8+255)/256), dim3(256), 0, stream>>>(enc_Wih_b, Wih16_b, 98304/8);
  k_cvtv<<<dim3((131072/8+255)/256), dim3(256), 0, stream>>>(proj_W, proj_W16, 131072/8);
  k_cvtv<<<dim3((229376/8+255)/256), dim3(256), 0, stream>>>(lin_W, lin_W16, 229376/8);
  k_cvtv<<<dim3((491520/8+255)/256), dim3(256), 0, stream>>>(dec_Wih, dWih16, 491520/8);
  k_cvtk<<<dim3(H3), dim3(32), 0, stream>>>(enc_Whh_f, W16_f, HDIM, 0);
  k_cvtk<<<dim3(H3), dim3(32), 0, stream>>>(enc_Whh_b, W16_b, HDIM, 0);
  k_cvtk<<<dim3(H3), dim3(64), 0, stream>>>(dec_Wih, dWck16, 640, 128);   // ctx cols, K=512
  k_cvtk<<<dim3(H3), dim3(32), 0, stream>>>(dec_Whh, dWhk16, HDIM, 0);    // K=256
  k_cvtk<<<dim3(HDIM), dim3(32), 0, stream>>>(attn_Wq, Wq16k, HDIM, 0);   // K=256

  // gi = emb @ Wih.T + bih (MFMA f16)
  k_gmm<<<dim3(6,100), dim3(256), 0, stream>>>(emb16, EDIM, Wih16_f, EDIM, enc_bih_f,
      gi_f, (_Float16*)nullptr, H3, SLEN*BATCH, H3, EDIM, 0);
  k_gmm<<<dim3(6,100), dim3(256), 0, stream>>>(emb16, EDIM, Wih16_b, EDIM, enc_bih_b,
      gi_b, (_Float16*)nullptr, H3, SLEN*BATCH, H3, EDIM, 1);

  k_enc<<<dim3(64), dim3(768), 0, stream>>>(gi_f, gi_b, W16_f, W16_b, enc_bhh_f, enc_bhh_b, enc_states);

  // post-enc conversions into the dead gi region
  k_cvtv<<<dim3((6553600/8+255)/256), dim3(256), 0, stream>>>(enc_states, enc16, 6553600/8);
  k_cvtv<<<dim3((12800000/8+255)/256), dim3(256), 0, stream>>>(out_W, out_W16, 12800000/8);

  // proj (f16 only) = enc_states @ proj_W.T + proj_b
  k_gmm<<<dim3(2,100), dim3(256), 0, stream>>>(enc16, 2*HDIM, proj_W16, 2*HDIM, proj_b,
      (float*)nullptr, proj16, HDIM, SLEN*BATCH, HDIM, 2*HDIM, 0);

  k_bridge<<<dim3(BATCH), dim3(256), 0, stream>>>(enc_states, bridge_W, bridge_b, hbuf0);

  // decoder-embedding gate contributions (K=128 e-cols of cat), MFMA
  k_gmm<<<dim3(6,4), dim3(256), 0, stream>>>(cat16, 896, dWih16, 640, dec_bih,
      gie_all, (_Float16*)nullptr, H3, NDEC*BATCH, H3, EDIM, 0);

  // 15 decoder steps: 2 wide kernels per step, h ping-pong
  float* hb[2] = {hbuf0, hbuf1};
  for (int t=0;t<NDEC;++t){
    k_attnB<<<dim3(8,32), dim3(256), 0, stream>>>(t, proj16, enc16, Wq16k, attn_We,
        hb[t&1], alphas_e, sum_part, ctx_part);
    k_gruD<<<dim3(8,32), dim3(256), 0, stream>>>(t, ctx_part, sum_part, gie_all,
        dWck16, dWhk16, dec_bhh, hb[t&1], hb[(t+1)&1], cat_all, cat16, sums_all);
  }

  // epilogue
  k_gmm<<<dim3(2,4), dim3(256), 0, stream>>>(cat16, 896, lin_W16, 896, lin_b,
      (float*)nullptr, lin16, HDIM, NDEC*BATCH, HDIM, 896, 0);
  k_pgen<<<dim3(NDEC*BATCH), dim3(64), 0, stream>>>(cat_all, pgen_W, pgen_b, pgen_all);
  k_gmm<<<dim3(391,4), dim3(256), 0, stream>>>(lin16, HDIM, out_W16, HDIM, out_b,
      (float*)nullptr, logits16, VVOC, NDEC*BATCH, VVOC, HDIM, 0);
  k_rowred<<<dim3(NDEC*BATCH), dim3(256), 0, stream>>>(logits16, row_max, row_sum);
  k_final<<<dim3(196, BATCH, TLEN), dim3(256), 0, stream>>>(logits16, pgen_all, row_max, row_sum, out);
  k_scatter<<<dim3(NDEC*BATCH), dim3(512), 0, stream>>>(input_seq_ext, alphas_e, sums_all, pgen_all, out);
  k_log<<<dim3(196, BATCH, NDEC), dim3(256), 0, stream>>>(out);
}

// Round 7
// 1176.484 us; speedup vs baseline: 5.7795x; 1.0181x over previous
//
#include <hip/hip_runtime.h>

#define SLEN 400
#define BATCH 32
#define TLEN 16
#define NDEC 15
#define EDIM 128
#define HDIM 256
#define H3 768
#define VVOC 50000
#define VEXT 50020
#define SCHUNK 50

// ---------- fast math helpers ----------
__device__ __forceinline__ float frcp(float x){ return __builtin_amdgcn_rcpf(x); }
__device__ __forceinline__ float fsig(float x){ return frcp(1.f + __expf(-x)); }
__device__ __forceinline__ float ftanh(float x){
  float e = __expf(2.f*x);
  return 1.f - 2.f*frcp(e + 1.f);
}

typedef _Float16 h2 __attribute__((ext_vector_type(2)));
typedef _Float16 half8 __attribute__((ext_vector_type(8)));
typedef float floatx4 __attribute__((ext_vector_type(4)));

__device__ __forceinline__ h2 u2h(unsigned u){ return __builtin_bit_cast(h2, u); }
__device__ __forceinline__ unsigned pkh(float a, float b){
  h2 v; v.x=(_Float16)a; v.y=(_Float16)b;
  return __builtin_bit_cast(unsigned, v);
}

#if __has_builtin(__builtin_amdgcn_fdot2)
__device__ __forceinline__ float fdot2h(h2 a, h2 b, float c){
  return __builtin_amdgcn_fdot2(a, b, c, false);
}
#else
__device__ __forceinline__ float fdot2h(h2 a, h2 b, float c){
  return fmaf((float)a.x,(float)b.x, fmaf((float)a.y,(float)b.y, c));
}
#endif

__device__ __forceinline__ float wred_sum(float v){
  #pragma unroll
  for (int o=32;o>0;o>>=1) v += __shfl_down(v,o,64);
  return v;
}
__device__ __forceinline__ float wred_max(float v){
  #pragma unroll
  for (int o=32;o>0;o>>=1) v = fmaxf(v, __shfl_down(v,o,64));
  return v;
}
__device__ __forceinline__ float block_max(float v, float* red){
  v = wred_max(v);
  int lane = threadIdx.x & 63, wid = threadIdx.x >> 6;
  if (!lane) red[wid] = v;
  __syncthreads();
  if (threadIdx.x == 0){
    float m = red[0];
    int nw = blockDim.x >> 6;
    for (int w=1;w<nw;++w) m = fmaxf(m, red[w]);
    red[0] = m;
  }
  __syncthreads();
  v = red[0];
  __syncthreads();
  return v;
}
__device__ __forceinline__ float block_sum(float v, float* red){
  v = wred_sum(v);
  int lane = threadIdx.x & 63, wid = threadIdx.x >> 6;
  if (!lane) red[wid] = v;
  __syncthreads();
  if (threadIdx.x == 0){
    float m = red[0];
    int nw = blockDim.x >> 6;
    for (int w=1;w<nw;++w) m += red[w];
    red[0] = m;
  }
  __syncthreads();
  v = red[0];
  __syncthreads();
  return v;
}

// ---------- embedding gather ----------
__global__ __launch_bounds__(64) void k_embed(
    const int* __restrict__ input_seq, const int* __restrict__ target_seq,
    const float* __restrict__ embedding,
    _Float16* __restrict__ emb16, float* __restrict__ cat_all, _Float16* __restrict__ cat16)
{
  int row = blockIdx.x;
  if (row < SLEN*BATCH) {
    int s = row >> 5, b = row & 31;
    int tok = input_seq[b*SLEN + s];
    float2 v = ((const float2*)(embedding + (size_t)tok*EDIM))[threadIdx.x];
    ((unsigned*)(emb16 + (size_t)row*EDIM))[threadIdx.x] = pkh(v.x, v.y);
  } else {
    int rr = row - SLEN*BATCH;
    int t = rr >> 5, b = rr & 31;
    int tok = target_seq[b*TLEN + t];       // toks = target_seq[:, :T-1].T
    float2 v = ((const float2*)(embedding + (size_t)tok*EDIM))[threadIdx.x];
    ((float2*)(cat_all + (size_t)rr*896))[threadIdx.x] = v;       // cat cols [0:128) = e
    ((unsigned*)(cat16 + (size_t)rr*896))[threadIdx.x] = pkh(v.x, v.y);
  }
}

// ---------- batched flat fp32 -> f16 converts (5 jobs in one launch) ----------
__global__ __launch_bounds__(256) void k_cvtv5(
    const float* __restrict__ S0, _Float16* __restrict__ D0, int n0,
    const float* __restrict__ S1, _Float16* __restrict__ D1, int n1,
    const float* __restrict__ S2, _Float16* __restrict__ D2, int n2,
    const float* __restrict__ S3, _Float16* __restrict__ D3, int n3,
    const float* __restrict__ S4, _Float16* __restrict__ D4, int n4)
{
  const float* S; _Float16* D; int n8;
  switch (blockIdx.y){
    case 0: S=S0; D=D0; n8=n0; break;
    case 1: S=S1; D=D1; n8=n1; break;
    case 2: S=S2; D=D2; n8=n2; break;
    case 3: S=S3; D=D3; n8=n3; break;
    default: S=S4; D=D4; n8=n4; break;
  }
  int i = blockIdx.x*256 + threadIdx.x;
  if (i >= n8) return;
  float4 a = ((const float4*)S)[i*2];
  float4 b = ((const float4*)S)[i*2+1];
  uint4 o;
  o.x = pkh(a.x,a.y); o.y = pkh(a.z,a.w);
  o.z = pkh(b.x,b.y); o.w = pkh(b.z,b.w);
  ((uint4*)D)[i] = o;
}

// ---------- single big fp32 -> f16 convert ----------
__global__ __launch_bounds__(256) void k_cvtv(
    const float* __restrict__ S, _Float16* __restrict__ D, int n8)
{
  int i = blockIdx.x*256 + threadIdx.x;
  if (i >= n8) return;
  float4 a = ((const float4*)S)[i*2];
  float4 b = ((const float4*)S)[i*2+1];
  uint4 o;
  o.x = pkh(a.x,a.y); o.y = pkh(a.z,a.w);
  o.z = pkh(b.x,b.y); o.w = pkh(b.z,b.w);
  ((uint4*)D)[i] = o;
}

// ---------- batched k-major f16 packers (5 jobs): D[k8][row] = 8 halves of W[row, coloff+k8*8..] ----------
__global__ __launch_bounds__(64) void k_cvtk5(
    const float* __restrict__ W0, uint4* __restrict__ D0,
    const float* __restrict__ W1, uint4* __restrict__ D1,
    const float* __restrict__ W2, uint4* __restrict__ D2,
    const float* __restrict__ W3, uint4* __restrict__ D3,
    const float* __restrict__ W4, uint4* __restrict__ D4)
{
  const float* W; uint4* D; int ldw, coloff, nrows, nk8;
  switch (blockIdx.y){
    case 0: W=W0; D=D0; ldw=HDIM; coloff=0;   nrows=H3;   nk8=32; break;  // enc_Whh_f
    case 1: W=W1; D=D1; ldw=HDIM; coloff=0;   nrows=H3;   nk8=32; break;  // enc_Whh_b
    case 2: W=W2; D=D2; ldw=640;  coloff=128; nrows=H3;   nk8=64; break;  // dec_Wih ctx cols
    case 3: W=W3; D=D3; ldw=HDIM; coloff=0;   nrows=H3;   nk8=32; break;  // dec_Whh
    default: W=W4; D=D4; ldw=HDIM; coloff=0;  nrows=HDIM; nk8=32; break;  // attn_Wq
  }
  int row = blockIdx.x, k8 = threadIdx.x;
  if (row >= nrows || k8 >= nk8) return;
  const float* s = W + (size_t)row*ldw + coloff + k8*8;
  float4 x = *(const float4*)s;
  float4 y = *(const float4*)(s+4);
  uint4 o;
  o.x = pkh(x.x,x.y); o.y = pkh(x.z,x.w);
  o.z = pkh(y.x,y.y); o.w = pkh(y.z,y.w);
  D[(size_t)k8*nrows + row] = o;
}

// ---------- MFMA f16 GEMM: C[m,n] = sum_k A16[am,k]*W16[n,k] + bias[n] ----------
__global__ __launch_bounds__(256) void k_gmm(
    const _Float16* __restrict__ A, int lda,
    const _Float16* __restrict__ W, int ldw,
    const float* __restrict__ bias,
    float* __restrict__ C, _Float16* __restrict__ C16, int ldc,
    int M, int N, int K, int rev)
{
  __shared__ __align__(16) _Float16 Al[128*64];
  __shared__ __align__(16) _Float16 Wl[128*64];
  int tid = threadIdx.x;
  int wv = tid >> 6, l = tid & 63;
  int wr = (wv>>1)*64, wc = (wv&1)*64;
  int lr = l & 15, lh = l >> 4;
  int m0 = blockIdx.y*128, n0 = blockIdx.x*128;
  floatx4 acc[4][4];
  #pragma unroll
  for (int i=0;i<4;++i)
    #pragma unroll
    for (int jn=0;jn<4;++jn) acc[i][jn] = (floatx4){0.f,0.f,0.f,0.f};

  for (int kc=0; kc<K; kc+=64){
    #pragma unroll
    for (int i=0;i<4;++i){
      int idx = tid + i*256;
      int row = idx>>3, c = idx&7;
      int m = m0+row;
      uint4 v = {0u,0u,0u,0u};
      if (m < M){
        int am = m;
        if (rev){ int s = m>>5; am = ((SLEN-1-s)<<5)|(m&31); }
        v = *(const uint4*)&A[(size_t)am*lda + kc + c*8];
      }
      *(uint4*)&Al[row*64 + ((c ^ (row&7))<<3)] = v;
    }
    #pragma unroll
    for (int i=0;i<4;++i){
      int idx = tid + i*256;
      int row = idx>>3, c = idx&7;
      int n = n0+row;
      uint4 v = {0u,0u,0u,0u};
      if (n < N) v = *(const uint4*)&W[(size_t)n*ldw + kc + c*8];
      *(uint4*)&Wl[row*64 + ((c ^ (row&7))<<3)] = v;
    }
    __syncthreads();
    #pragma unroll
    for (int ks=0; ks<2; ++ks){
      half8 af0, af1, af2, af3, bf0, bf1, bf2, bf3;
      {
        int c = ks*4 + lh;
        int r0 = wr + 0*16 + lr, r1 = wr + 1*16 + lr, r2 = wr + 2*16 + lr, r3 = wr + 3*16 + lr;
        af0 = *(const half8*)&Al[r0*64 + ((c ^ (r0&7))<<3)];
        af1 = *(const half8*)&Al[r1*64 + ((c ^ (r1&7))<<3)];
        af2 = *(const half8*)&Al[r2*64 + ((c ^ (r2&7))<<3)];
        af3 = *(const half8*)&Al[r3*64 + ((c ^ (r3&7))<<3)];
        int n0l = wc + 0*16 + lr, n1l = wc + 1*16 + lr, n2l = wc + 2*16 + lr, n3l = wc + 3*16 + lr;
        bf0 = *(const half8*)&Wl[n0l*64 + ((c ^ (n0l&7))<<3)];
        bf1 = *(const half8*)&Wl[n1l*64 + ((c ^ (n1l&7))<<3)];
        bf2 = *(const half8*)&Wl[n2l*64 + ((c ^ (n2l&7))<<3)];
        bf3 = *(const half8*)&Wl[n3l*64 + ((c ^ (n3l&7))<<3)];
      }
      half8 afs[4] = {af0, af1, af2, af3};
      half8 bfs[4] = {bf0, bf1, bf2, bf3};
      #pragma unroll
      for (int mi=0;mi<4;++mi)
        #pragma unroll
        for (int ni=0;ni<4;++ni)
          acc[mi][ni] = __builtin_amdgcn_mfma_f32_16x16x32_f16(afs[mi], bfs[ni], acc[mi][ni], 0,0,0);
    }
    __syncthreads();
  }
  #pragma unroll
  for (int mi=0;mi<4;++mi){
    #pragma unroll
    for (int q=0;q<4;++q){
      int m = m0 + wr + mi*16 + lh*4 + q;
      if (m < M){
        #pragma unroll
        for (int ni=0;ni<4;++ni){
          int n = n0 + wc + ni*16 + lr;
          if (n < N){
            float v = acc[mi][ni][q] + bias[n];
            if (C)   C[(size_t)m*ldc + n] = v;
            if (C16) C16[(size_t)m*ldc + n] = (_Float16)v;
          }
        }
      }
    }
  }
}

// ---------- encoder GRU recurrence: 12 chunks LDS + 20 chunks PERSISTENT REGISTERS ----------
// block = (dir, b), 768 threads (3 waves/SIMD -> VGPR cap ~170; 80 weight regs + ~50 work fits).
// Round 6 measured 73.6 B/cyc/CU on the 20-chunk L2 re-stream = per-CU L2 port ceiling;
// persisting those chunks in registers removes the per-step weight traffic entirely.
#define R20(M) M(0) M(1) M(2) M(3) M(4) M(5) M(6) M(7) M(8) M(9) \
               M(10) M(11) M(12) M(13) M(14) M(15) M(16) M(17) M(18) M(19)

__global__ __launch_bounds__(768) void k_enc(
    const float* __restrict__ gi_f, const float* __restrict__ gi_b,
    const uint4* __restrict__ W16_f, const uint4* __restrict__ W16_b,
    const float* __restrict__ bhh_f, const float* __restrict__ bhh_b,
    _Float16* __restrict__ enc16, float* __restrict__ hfin)
{
  int dir = blockIdx.x >> 5, b = blockIdx.x & 31;
  int jj = threadIdx.x;
  const float* gi  = dir ? gi_b  : gi_f;
  const uint4* Wp  = (dir ? W16_b : W16_f) + jj;
  float bh = (dir ? bhh_b : bhh_f)[jj];

  __shared__ __align__(16) unsigned hpk[HDIM/2];
  __shared__ __align__(16) float st[H3];
  __shared__ uint4 Wlds[12][H3];

  #pragma unroll
  for (int k8=0;k8<12;++k8) Wlds[k8][jj] = Wp[k8*H3];

  // persistent weight registers: chunks 12..31 (named -> cannot be demoted to alloca)
#define DW(i) uint4 q##i = Wp[(12+(i))*H3];
  R20(DW)
#undef DW

  if (jj < HDIM/2) hpk[jj] = 0u;
  float hreg = 0.f;
  _Float16* dst = enc16 + (size_t)b*2*HDIM + dir*HDIM + jj;
  __syncthreads();

  for (int s=0;s<SLEN;++s){
    const float* grow = gi + ((size_t)s*BATCH + b)*H3;
    float g1 = 0.f, g2 = 0.f;
    if (jj < 512)  g1 = grow[jj];
    if (jj < HDIM) g2 = grow[2*HDIM + jj];
    float ac0=0.f, ac1=0.f, ac2=0.f, ac3=0.f;
    #pragma unroll
    for (int k8=0;k8<12;++k8){
      uint4 w = Wlds[k8][jj];
      uint4 hq = *(const uint4*)&hpk[k8*4];
      ac0 = fdot2h(u2h(w.x),u2h(hq.x),ac0);
      ac1 = fdot2h(u2h(w.y),u2h(hq.y),ac1);
      ac2 = fdot2h(u2h(w.z),u2h(hq.z),ac2);
      ac3 = fdot2h(u2h(w.w),u2h(hq.w),ac3);
    }
#define DU(i) { uint4 hq = *(const uint4*)&hpk[(12+(i))*4]; \
    ac0 = fdot2h(u2h(q##i.x),u2h(hq.x),ac0); \
    ac1 = fdot2h(u2h(q##i.y),u2h(hq.y),ac1); \
    ac2 = fdot2h(u2h(q##i.z),u2h(hq.z),ac2); \
    ac3 = fdot2h(u2h(q##i.w),u2h(hq.w),ac3); }
    R20(DU)
#undef DU
    float acc = (ac0+ac1)+(ac2+ac3) + bh;
    st[jj] = (jj < 512) ? (acc + g1) : acc;
    __syncthreads();
    if (jj < HDIM){
      float rr = fsig(st[jj]);
      float zz = fsig(st[HDIM + jj]);
      float nn = ftanh(g2 + rr*st[2*HDIM + jj]);
      float h2v = nn + zz*(hreg - nn);
      hreg = h2v;
      int srow = dir ? (SLEN-1-s) : s;
      dst[(size_t)srow*BATCH*2*HDIM] = (_Float16)h2v;
      ((_Float16*)hpk)[jj] = (_Float16)h2v;
      if (s == SLEN-1) hfin[(size_t)(dir*BATCH + b)*HDIM + jj] = h2v;
    }
    __syncthreads();
  }
}

// ---------- bridge: h0 = tanh([hf,hb] @ bridge_W.T + b) ----------
__global__ __launch_bounds__(256) void k_bridge(
    const float* __restrict__ hfin,
    const float* __restrict__ bridge_W, const float* __restrict__ bridge_b,
    float* __restrict__ h_out)
{
  int b = blockIdx.x, j = threadIdx.x;
  __shared__ float hcat[2*HDIM];
  hcat[j]        = hfin[(size_t)b*HDIM + j];                 // forward final
  hcat[HDIM + j] = hfin[(size_t)(BATCH + b)*HDIM + j];       // backward final
  __syncthreads();
  const float* w = bridge_W + (size_t)j*2*HDIM;
  float4 a = {0.f,0.f,0.f,0.f};
  #pragma unroll 4
  for (int k=0;k<2*HDIM;k+=4){
    float4 h4 = *(const float4*)&hcat[k];
    float4 w4 = *(const float4*)&w[k];
    a.x=fmaf(h4.x,w4.x,a.x); a.y=fmaf(h4.y,w4.y,a.y);
    a.z=fmaf(h4.z,w4.z,a.z); a.w=fmaf(h4.w,w4.w,a.w);
  }
  h_out[b*HDIM+j] = ftanh((a.x+a.y)+(a.z+a.w) + bridge_b[j]);
}

// ---------- decoder step part B: q + attention scores + e + partial sums/ctx ----------
// grid (8 s-chunks, 32 b) x 256 thr. No max-subtraction: |score| <= ||We||_1 (~4), exp safe.
__global__ __launch_bounds__(256) void k_attnB(
    int t,
    const _Float16* __restrict__ proj16,
    const _Float16* __restrict__ enc16,
    const uint4* __restrict__ Wq16k,
    const float* __restrict__ attn_We,
    const float* __restrict__ hin,
    float* __restrict__ alphas_e,
    float* __restrict__ sum_part,
    float* __restrict__ ctx_part)
{
  int ch = blockIdx.x, b = blockIdx.y;
  int tid = threadIdx.x;
  __shared__ float q_s[HDIM], we_s[HDIM], sc[SCHUNK], red[8];
  __shared__ __align__(16) unsigned hq[HDIM/2];

  we_s[tid] = attn_We[tid];
  if (tid < HDIM/2){
    float2 hv = *(const float2*)&hin[b*HDIM + tid*2];
    hq[tid] = pkh(hv.x, hv.y);
  }
  __syncthreads();
  // q[i] = sum_k Wq[i,k] h[k]
  {
    float a0=0.f,a1=0.f,a2=0.f,a3=0.f;
    #pragma unroll
    for (int k8=0;k8<32;++k8){
      uint4 w = Wq16k[(size_t)k8*HDIM + tid];
      uint4 hp = *(const uint4*)&hq[k8*4];
      a0 = fdot2h(u2h(w.x),u2h(hp.x),a0);
      a1 = fdot2h(u2h(w.y),u2h(hp.y),a1);
      a2 = fdot2h(u2h(w.z),u2h(hp.z),a2);
      a3 = fdot2h(u2h(w.w),u2h(hp.w),a3);
    }
    q_s[tid] = (a0+a1)+(a2+a3);
  }
  __syncthreads();
  // scores: wave w handles s-rows ch*50 + {w, w+4, ...}
  {
    int wave = tid >> 6, lane = tid & 63;
    int d0 = lane*4;
    float4 qv = *(const float4*)&q_s[d0];
    float4 wv = *(const float4*)&we_s[d0];
    for (int is = wave; is < SCHUNK; is += 4){
      int s = ch*SCHUNK + is;
      uint2 p = *(const uint2*)&proj16[((size_t)(s*BATCH + b))*HDIM + d0];
      h2 pa = u2h(p.x), pb = u2h(p.y);
      float v = ftanh(qv.x+(float)pa.x)*wv.x + ftanh(qv.y+(float)pa.y)*wv.y
              + ftanh(qv.z+(float)pb.x)*wv.z + ftanh(qv.w+(float)pb.y)*wv.w;
      v = wred_sum(v);
      if (lane == 0){
        float e = __expf(v);
        sc[is] = e;
        alphas_e[((size_t)t*SLEN + s)*BATCH + b] = e;
      }
    }
  }
  __syncthreads();
  // partial sum of e
  {
    float sv = (tid < SCHUNK) ? sc[tid] : 0.f;
    sv = block_sum(sv, red);
    if (tid == 0) sum_part[b*8 + ch] = sv;
  }
  // partial ctx: thread owns d = 2t, 2t+1
  {
    float a0=0.f, a1=0.f;
    for (int is=0; is<SCHUNK; ++is){
      int s = ch*SCHUNK + is;
      unsigned u = *(const unsigned*)&enc16[((size_t)(s*BATCH + b) << 9) + tid*2];
      h2 ev = u2h(u);
      float e = sc[is];
      a0 = fmaf(e, (float)ev.x, a0);
      a1 = fmaf(e, (float)ev.y, a1);
    }
    float2 o; o.x = a0; o.y = a1;
    *(float2*)&ctx_part[(((size_t)b*8 + ch) << 9) + tid*2] = o;
  }
}

// ---------- decoder step part D: ctx reduce + GRU + h/cat writes ----------
__global__ __launch_bounds__(256) void k_gruD(
    int t,
    const float* __restrict__ ctx_part,
    const float* __restrict__ sum_part,
    const float* __restrict__ gie_all,
    const uint4* __restrict__ dWck16,
    const uint4* __restrict__ dWhk16,
    const float* __restrict__ dec_bhh,
    const float* __restrict__ hin,
    float* __restrict__ hout,
    float* __restrict__ cat_all, _Float16* __restrict__ cat16,
    float* __restrict__ sums_all)
{
  int ch = blockIdx.x, b = blockIdx.y;
  int tid = threadIdx.x;
  int jl = tid & 31, slice = tid >> 5;
  __shared__ __align__(16) unsigned cpk[HDIM], hpk[HDIM/2];
  __shared__ float hf[HDIM];
  __shared__ float pc[3][8][32], ph[3][8][32];
  __shared__ float invs;

  if (tid == 0){
    float ssum = 0.f;
    #pragma unroll
    for (int c=0;c<8;++c) ssum += sum_part[b*8 + c];
    float inv = 1.f/ssum;
    invs = inv;
    if (ch == 0) sums_all[t*BATCH + b] = inv;
  }
  if (tid < HDIM/2){
    float2 hv = *(const float2*)&hin[b*HDIM + tid*2];
    hpk[tid] = pkh(hv.x, hv.y);
    hf[tid*2] = hv.x; hf[tid*2+1] = hv.y;
  }
  __syncthreads();
  // ctx reduce + normalize; pack f16; chunk0 writes cat
  {
    int d0 = tid*2;
    float c0=0.f, c1=0.f;
    #pragma unroll
    for (int c=0;c<8;++c){
      float2 v = *(const float2*)&ctx_part[(((size_t)b*8 + c) << 9) + d0];
      c0 += v.x; c1 += v.y;
    }
    c0 *= invs; c1 *= invs;
    cpk[tid] = pkh(c0, c1);
    if (ch == 0){
      int r = t*BATCH + b;
      cat_all[(size_t)r*896 + 384 + d0]     = c0;
      cat_all[(size_t)r*896 + 384 + d0 + 1] = c1;
      cat16[(size_t)r*896 + 384 + d0]     = (_Float16)c0;
      cat16[(size_t)r*896 + 384 + d0 + 1] = (_Float16)c1;
    }
  }
  __syncthreads();
  // gate dots: 3 gates, ctx(K=512) + h(K=256), k-slice per thread
  {
    int jb = ch*32 + jl;
    float c0=0.f,c1=0.f,c2=0.f, g0=0.f,g1=0.f,g2=0.f;
    #pragma unroll
    for (int i=0;i<8;++i){
      int k8 = slice*8 + i;
      uint4 hq = *(const uint4*)&cpk[k8*4];
      uint4 w0 = dWck16[(size_t)k8*H3 + jb];
      uint4 w1 = dWck16[(size_t)k8*H3 + 256 + jb];
      uint4 w2 = dWck16[(size_t)k8*H3 + 512 + jb];
      c0 = fdot2h(u2h(w0.x),u2h(hq.x),c0); c0 = fdot2h(u2h(w0.y),u2h(hq.y),c0);
      c0 = fdot2h(u2h(w0.z),u2h(hq.z),c0); c0 = fdot2h(u2h(w0.w),u2h(hq.w),c0);
      c1 = fdot2h(u2h(w1.x),u2h(hq.x),c1); c1 = fdot2h(u2h(w1.y),u2h(hq.y),c1);
      c1 = fdot2h(u2h(w1.z),u2h(hq.z),c1); c1 = fdot2h(u2h(w1.w),u2h(hq.w),c1);
      c2 = fdot2h(u2h(w2.x),u2h(hq.x),c2); c2 = fdot2h(u2h(w2.y),u2h(hq.y),c2);
      c2 = fdot2h(u2h(w2.z),u2h(hq.z),c2); c2 = fdot2h(u2h(w2.w),u2h(hq.w),c2);
    }
    #pragma unroll
    for (int i=0;i<4;++i){
      int k8 = slice*4 + i;
      uint4 hq = *(const uint4*)&hpk[k8*4];
      uint4 w0 = dWhk16[(size_t)k8*H3 + jb];
      uint4 w1 = dWhk16[(size_t)k8*H3 + 256 + jb];
      uint4 w2 = dWhk16[(size_t)k8*H3 + 512 + jb];
      g0 = fdot2h(u2h(w0.x),u2h(hq.x),g0); g0 = fdot2h(u2h(w0.y),u2h(hq.y),g0);
      g0 = fdot2h(u2h(w0.z),u2h(hq.z),g0); g0 = fdot2h(u2h(w0.w),u2h(hq.w),g0);
      g1 = fdot2h(u2h(w1.x),u2h(hq.x),g1); g1 = fdot2h(u2h(w1.y),u2h(hq.y),g1);
      g1 = fdot2h(u2h(w1.z),u2h(hq.z),g1); g1 = fdot2h(u2h(w1.w),u2h(hq.w),g1);
      g2 = fdot2h(u2h(w2.x),u2h(hq.x),g2); g2 = fdot2h(u2h(w2.y),u2h(hq.y),g2);
      g2 = fdot2h(u2h(w2.z),u2h(hq.z),g2); g2 = fdot2h(u2h(w2.w),u2h(hq.w),g2);
    }
    pc[0][slice][jl]=c0; pc[1][slice][jl]=c1; pc[2][slice][jl]=c2;
    ph[0][slice][jl]=g0; ph[1][slice][jl]=g1; ph[2][slice][jl]=g2;
  }
  __syncthreads();
  if (tid < 32){
    int j = tid, r = t*BATCH + b;
    int jj = ch*32 + j;
    float gi0 = gie_all[(size_t)r*H3 + jj];
    float gi1 = gie_all[(size_t)r*H3 + 256 + jj];
    float gi2 = gie_all[(size_t)r*H3 + 512 + jj];
    float gh0 = dec_bhh[jj], gh1 = dec_bhh[256 + jj], gh2 = dec_bhh[512 + jj];
    #pragma unroll
    for (int c=0;c<8;++c){
      gi0 += pc[0][c][j]; gi1 += pc[1][c][j]; gi2 += pc[2][c][j];
      gh0 += ph[0][c][j]; gh1 += ph[1][c][j]; gh2 += ph[2][c][j];
    }
    float rr = fsig(gi0 + gh0);
    float zz = fsig(gi1 + gh1);
    float nn = ftanh(gi2 + rr*gh2);
    float hp = hf[jj];
    float h2v = nn + zz*(hp - nn);
    hout[b*HDIM + jj] = h2v;
    cat_all[(size_t)r*896 + 128 + jj] = h2v;
    cat16[(size_t)r*896 + 128 + jj] = (_Float16)h2v;
  }
}

// ---------- p_gen = sigmoid(cat . pgen_W + b) ----------
__global__ __launch_bounds__(64) void k_pgen(
    const float* __restrict__ cat_all,
    const float* __restrict__ pgen_W, const float* __restrict__ pgen_b,
    float* __restrict__ pgen_all)
{
  int r = blockIdx.x;
  const float* c = cat_all + (size_t)r*896;
  float acc = 0.f;
  for (int k=threadIdx.x; k<896; k+=64) acc = fmaf(c[k], pgen_W[k], acc);
  acc = wred_sum(acc);
  if (threadIdx.x==0) pgen_all[r] = fsig(acc + pgen_b[0]);
}

// ---------- per-row softmax stats over V (f16 logits) ----------
__global__ __launch_bounds__(256) void k_rowred(
    const _Float16* __restrict__ logits,
    float* __restrict__ row_max, float* __restrict__ row_sum)
{
  int r = blockIdx.x;
  const uint4* row = (const uint4*)(logits + (size_t)r*VVOC);
  __shared__ float red[8];
  float m = -1e30f;
  for (int v=threadIdx.x; v<VVOC/8; v+=256){
    uint4 x = row[v];
    h2 a=u2h(x.x), bb=u2h(x.y), c=u2h(x.z), d=u2h(x.w);
    float m1 = fmaxf(fmaxf((float)a.x,(float)a.y), fmaxf((float)bb.x,(float)bb.y));
    float m2 = fmaxf(fmaxf((float)c.x,(float)c.y), fmaxf((float)d.x,(float)d.y));
    m = fmaxf(m, fmaxf(m1,m2));
  }
  m = block_max(m, red);
  float s = 0.f;
  for (int v=threadIdx.x; v<VVOC/8; v+=256){
    uint4 x = row[v];
    h2 a=u2h(x.x), bb=u2h(x.y), c=u2h(x.z), d=u2h(x.w);
    s += __expf((float)a.x-m) + __expf((float)a.y-m) + __expf((float)bb.x-m) + __expf((float)bb.y-m)
       + __expf((float)c.x-m) + __expf((float)c.y-m) + __expf((float)d.x-m) + __expf((float)d.y-m);
  }
  s = block_sum(s, red);
  if (threadIdx.x==0){ row_max[r]=m; row_sum[r]=1.f/s; }
}

// ---------- write ext (linear domain); t=0 row = 0 ----------
__global__ __launch_bounds__(256) void k_final(
    const _Float16* __restrict__ logits, const float* __restrict__ pgen_all,
    const float* __restrict__ row_max, const float* __restrict__ row_sum,
    float* __restrict__ out)
{
  int v = blockIdx.x*256 + threadIdx.x;
  if (v >= VEXT) return;
  int b = blockIdx.y, t = blockIdx.z;
  size_t o = ((size_t)t*BATCH + b)*VEXT + v;
  if (t == 0){ out[o] = 0.f; return; }
  int r = (t-1)*BATCH + b;
  float val = 1e-12f;
  if (v < VVOC)
    val += pgen_all[r] * row_sum[r] * __expf((float)logits[(size_t)r*VVOC + v] - row_max[r]);
  out[o] = val;
}

// ---------- scatter copy-distribution (alphas = e * inv_sum) ----------
__global__ __launch_bounds__(512) void k_scatter(
    const int* __restrict__ input_seq_ext,
    const float* __restrict__ alphas_e, const float* __restrict__ sums_all,
    const float* __restrict__ pgen_all,
    float* __restrict__ out)
{
  int r = blockIdx.x;               // t*32+b
  int s = threadIdx.x;
  if (s >= SLEN) return;
  int t = r >> 5, b = r & 31;
  float w = (1.f - pgen_all[r]) * alphas_e[((size_t)t*SLEN + s)*BATCH + b] * sums_all[r];
  int idx = input_seq_ext[b*SLEN + s];
  atomicAdd(&out[((size_t)(t+1)*BATCH + b)*VEXT + idx], w);
}

// ---------- log transform rows t>=1 ----------
__global__ __launch_bounds__(256) void k_log(float* __restrict__ out)
{
  int v = blockIdx.x*256 + threadIdx.x;
  if (v >= VEXT) return;
  int b = blockIdx.y, t = blockIdx.z + 1;
  size_t o = ((size_t)t*BATCH + b)*VEXT + v;
  out[o] = __logf(out[o]);
}

extern "C" void kernel_launch(void* const* d_in, const int* in_sizes, int n_in,
                              void* d_out, int out_size, void* d_ws, size_t ws_size,
                              hipStream_t stream)
{
  (void)in_sizes; (void)n_in; (void)out_size; (void)ws_size;
  const int*   input_seq     = (const int*)d_in[0];
  const int*   input_seq_ext = (const int*)d_in[1];
  const int*   target_seq    = (const int*)d_in[2];
  const float* embedding     = (const float*)d_in[3];
  const float* enc_Wih_f     = (const float*)d_in[4];
  const float* enc_Whh_f     = (const float*)d_in[5];
  const float* enc_bih_f     = (const float*)d_in[6];
  const float* enc_bhh_f     = (const float*)d_in[7];
  const float* enc_Wih_b     = (const float*)d_in[8];
  const float* enc_Whh_b     = (const float*)d_in[9];
  const float* enc_bih_b     = (const float*)d_in[10];
  const float* enc_bhh_b     = (const float*)d_in[11];
  const float* proj_W        = (const float*)d_in[12];
  const float* proj_b        = (const float*)d_in[13];
  const float* bridge_W      = (const float*)d_in[14];
  const float* bridge_b      = (const float*)d_in[15];
  const float* dec_Wih       = (const float*)d_in[16];
  const float* dec_Whh       = (const float*)d_in[17];
  const float* dec_bih       = (const float*)d_in[18];
  const float* dec_bhh       = (const float*)d_in[19];
  const float* attn_Wq       = (const float*)d_in[20];
  const float* attn_We       = (const float*)d_in[21];
  const float* lin_W         = (const float*)d_in[22];
  const float* lin_b         = (const float*)d_in[23];
  const float* pgen_W        = (const float*)d_in[24];
  const float* pgen_b        = (const float*)d_in[25];
  const float* out_W         = (const float*)d_in[26];
  const float* out_b         = (const float*)d_in[27];
  float* out = (float*)d_out;
  float* ws  = (float*)d_ws;

  // ---- workspace layout (float offsets); ~146 MB
  _Float16* emb16    = (_Float16*)(ws + 0);            // 409600 f
  _Float16* Wih16_f  = (_Float16*)(ws + 409600);       // 49152 f
  _Float16* Wih16_b  = (_Float16*)(ws + 458752);       // 49152 f
  _Float16* proj_W16 = (_Float16*)(ws + 507904);       // 65536 f
  _Float16* lin_W16  = (_Float16*)(ws + 573440);       // 114688 f
  _Float16* cat16    = (_Float16*)(ws + 688128);       // 215040 f
  _Float16* lin16    = (_Float16*)(ws + 903168);       // 61440 f
  _Float16* dWih16   = (_Float16*)(ws + 964608);       // 245760 f -> 1210368
  _Float16* enc16    = (_Float16*)(ws + 1638400);      // 3276800 f (k_enc writes f16 directly)
  float* hfin        = ws + 4915200;                   // 16384 f (final h, fp32)
  _Float16* proj16   = (_Float16*)(ws + 8192000);      // 1638400 f
  float* gi_f        = ws + 11468800;                  // 9830400 [dies after k_enc]
  float* gi_b        = ws + 21299200;                  // 9830400 [dies after k_enc]
  _Float16* logits16 = (_Float16*)(ws + 11468800);     // 12000000 f (post-enc)
  _Float16* out_W16  = (_Float16*)(ws + 23468800);     // 6400000 f (post-enc)
  // region [33145600, 35000000): decoder-step buffers (outside gi live range)
  uint4* Wq16k       = (uint4*)(ws + 33145600);        // 32768 f
  uint4* dWck16      = (uint4*)(ws + 33178368);        // 196608 f
  uint4* dWhk16      = (uint4*)(ws + 33374976);        // 98304 f
  float* ctx_part    = ws + 33473280;                  // 131072 f
  float* sum_part    = ws + 33604352;                  // 256 f
  float* sums_all    = ws + 33604608;                  // 480 f
  float* hbuf0       = ws + 33605088;                  // 8192 f
  float* hbuf1       = ws + 33613280;                  // 8192 f
  uint4* W16_f       = (uint4*)(ws + 35000000);        // 98304 f
  uint4* W16_b       = (uint4*)(ws + 35098304);        // 98304 f
  float* cat_all     = ws + 35468800;                  // 430080
  float* gie_all     = ws + 35898880;                  // 368640
  float* alphas_e    = ws + 36275712;                  // 192000
  float* pgen_all    = ws + 36467712;                  // 480
  float* row_max     = ws + 36468192;                  // 480
  float* row_sum     = ws + 36468672;                  // 480

  k_embed<<<dim3(SLEN*BATCH + NDEC*BATCH), dim3(64), 0, stream>>>(
      input_seq, target_seq, embedding, emb16, cat_all, cat16);

  // batched weight conversions (2 launches instead of 10)
  k_cvtv5<<<dim3(240, 5), dim3(256), 0, stream>>>(
      enc_Wih_f, Wih16_f, 12288,
      enc_Wih_b, Wih16_b, 12288,
      proj_W,    proj_W16, 16384,
      lin_W,     lin_W16,  28672,
      dec_Wih,   dWih16,   61440);
  k_cvtk5<<<dim3(H3, 5), dim3(64), 0, stream>>>(
      enc_Whh_f, W16_f,
      enc_Whh_b, W16_b,
      dec_Wih,   dWck16,
      dec_Whh,   dWhk16,
      attn_Wq,   Wq16k);

  // gi = emb @ Wih.T + bih (MFMA f16)
  k_gmm<<<dim3(6,100), dim3(256), 0, stream>>>(emb16, EDIM, Wih16_f, EDIM, enc_bih_f,
      gi_f, (_Float16*)nullptr, H3, SLEN*BATCH, H3, EDIM, 0);
  k_gmm<<<dim3(6,100), dim3(256), 0, stream>>>(emb16, EDIM, Wih16_b, EDIM, enc_bih_b,
      gi_b, (_Float16*)nullptr, H3, SLEN*BATCH, H3, EDIM, 1);

  k_enc<<<dim3(64), dim3(768), 0, stream>>>(gi_f, gi_b, W16_f, W16_b, enc_bhh_f, enc_bhh_b,
      enc16, hfin);

  // out_W conversion into the dead gi region (post-enc)
  k_cvtv<<<dim3((12800000/8+255)/256), dim3(256), 0, stream>>>(out_W, out_W16, 12800000/8);

  // proj (f16 only) = enc16 @ proj_W.T + proj_b
  k_gmm<<<dim3(2,100), dim3(256), 0, stream>>>(enc16, 2*HDIM, proj_W16, 2*HDIM, proj_b,
      (float*)nullptr, proj16, HDIM, SLEN*BATCH, HDIM, 2*HDIM, 0);

  k_bridge<<<dim3(BATCH), dim3(256), 0, stream>>>(hfin, bridge_W, bridge_b, hbuf0);

  // decoder-embedding gate contributions (K=128 e-cols of cat), MFMA
  k_gmm<<<dim3(6,4), dim3(256), 0, stream>>>(cat16, 896, dWih16, 640, dec_bih,
      gie_all, (_Float16*)nullptr, H3, NDEC*BATCH, H3, EDIM, 0);

  // 15 decoder steps: 2 wide kernels per step, h ping-pong
  float* hb[2] = {hbuf0, hbuf1};
  for (int t=0;t<NDEC;++t){
    k_attnB<<<dim3(8,32), dim3(256), 0, stream>>>(t, proj16, enc16, Wq16k, attn_We,
        hb[t&1], alphas_e, sum_part, ctx_part);
    k_gruD<<<dim3(8,32), dim3(256), 0, stream>>>(t, ctx_part, sum_part, gie_all,
        dWck16, dWhk16, dec_bhh, hb[t&1], hb[(t+1)&1], cat_all, cat16, sums_all);
  }

  // epilogue
  k_gmm<<<dim3(2,4), dim3(256), 0, stream>>>(cat16, 896, lin_W16, 896, lin_b,
      (float*)nullptr, lin16, HDIM, NDEC*BATCH, HDIM, 896, 0);
  k_pgen<<<dim3(NDEC*BATCH), dim3(64), 0, stream>>>(cat_all, pgen_W, pgen_b, pgen_all);
  k_gmm<<<dim3(391,4), dim3(256), 0, stream>>>(lin16, HDIM, out_W16, HDIM, out_b,
      (float*)nullptr, logits16, VVOC, NDEC*BATCH, VVOC, HDIM, 0);
  k_rowred<<<dim3(NDEC*BATCH), dim3(256), 0, stream>>>(logits16, row_max, row_sum);
  k_final<<<dim3(196, BATCH, TLEN), dim3(256), 0, stream>>>(logits16, pgen_all, row_max, row_sum, out);
  k_scatter<<<dim3(NDEC*BATCH), dim3(512), 0, stream>>>(input_seq_ext, alphas_e, sums_all, pgen_all, out);
  k_log<<<dim3(196, BATCH, NDEC), dim3(256), 0, stream>>>(out);
}